// Round 1
// baseline (377.537 us; speedup 1.0000x reference)
//
#include <hip/hip_runtime.h>
#include <hip/hip_bf16.h>

// Problem constants
#define Bn 2
#define Qn 21760
#define BQ 43520        // Bn*Qn
#define Dn 256
#define NHn 8
#define HDn 32
#define HWSUM 21760     // 128^2 + 64^2 + 32^2 + 16^2

// ---------------------------------------------------------------------------
// Transpose feats (B, C=256, H, W) fp32 -> (B, pos, C) bf16, levels concat.
// grid: (B * HWSUM/32 = 1360, 8 channel-tiles), block 256
// ---------------------------------------------------------------------------
__global__ __launch_bounds__(256) void feat_transpose_kernel(
    const float* __restrict__ f0, const float* __restrict__ f1,
    const float* __restrict__ f2, const float* __restrict__ f3,
    __hip_bfloat16* __restrict__ ft)
{
    __shared__ float tile[32][33];
    int bidx = blockIdx.x;
    int b = bidx / 680;
    int pos0 = (bidx - b * 680) * 32;
    int c0 = blockIdx.y * 32;
    int lvl = (pos0 >= 21504) ? 3 : (pos0 >= 20480) ? 2 : (pos0 >= 16384) ? 1 : 0;
    int HW = 16384 >> (2 * lvl);
    int base = (65536 - (65536 >> (2 * lvl))) / 3;   // 0,16384,20480,21504
    const float* f = (lvl == 0) ? f0 : (lvl == 1) ? f1 : (lvl == 2) ? f2 : f3;
    const float* src = f + (size_t)(b * 256 + c0) * HW + (pos0 - base);
    int tx = threadIdx.x & 31, ty = threadIdx.x >> 5;
#pragma unroll
    for (int cc = ty; cc < 32; cc += 8)
        tile[cc][tx] = src[(size_t)cc * HW + tx];
    __syncthreads();
#pragma unroll
    for (int ii = ty; ii < 32; ii += 8) {
        __hip_bfloat16* dst = ft + (size_t)(b * HWSUM + pos0 + ii) * 256 + c0;
        dst[tx] = __float2bfloat16(tile[tx][ii]);
    }
}

// ---------------------------------------------------------------------------
// fp32 GEMM: C[M,N] = A[M,256] @ W[256,N] + bias ; mode 1 -> tanh epilogue
// 64x64 tile, BK=16, 256 threads, 4x4 microtile.
// grid (M/64, N/64)
// ---------------------------------------------------------------------------
__global__ __launch_bounds__(256) void gemm_kernel(
    const float* __restrict__ A, const float* __restrict__ Wm,
    const float* __restrict__ bias, float* __restrict__ C,
    int N, int mode)
{
    __shared__ float As[16][64];
    __shared__ float Bs[16][64];
    int tid = threadIdx.x;
    int m0 = blockIdx.x * 64, n0 = blockIdx.y * 64;
    int tm = tid >> 4, tn = tid & 15;
    int ar = tid >> 2, ak = (tid & 3) * 4;
    int bk = tid >> 4, bj = (tid & 15) * 4;
    const float* Aload = A + (size_t)(m0 + ar) * 256 + ak;
    const float* Bload = Wm + (size_t)bk * N + n0 + bj;
    float acc[4][4] = {{0.0f}};
    for (int kt = 0; kt < 256; kt += 16) {
        float4 a = *(const float4*)(Aload + kt);
        float4 bb = *(const float4*)(Bload + (size_t)kt * N);
        *(float4*)&Bs[bk][bj] = bb;
        As[ak + 0][ar] = a.x;
        As[ak + 1][ar] = a.y;
        As[ak + 2][ar] = a.z;
        As[ak + 3][ar] = a.w;
        __syncthreads();
#pragma unroll
        for (int kk = 0; kk < 16; ++kk) {
            float4 av = *(const float4*)&As[kk][tm * 4];
            float4 bv = *(const float4*)&Bs[kk][tn * 4];
            float am[4] = {av.x, av.y, av.z, av.w};
            float bm[4] = {bv.x, bv.y, bv.z, bv.w};
#pragma unroll
            for (int i = 0; i < 4; ++i)
#pragma unroll
                for (int j = 0; j < 4; ++j)
                    acc[i][j] += am[i] * bm[j];
        }
        __syncthreads();
    }
    float4 bsv = *(const float4*)&bias[n0 + tn * 4];
    float bia[4] = {bsv.x, bsv.y, bsv.z, bsv.w};
#pragma unroll
    for (int i = 0; i < 4; ++i) {
        float o[4];
#pragma unroll
        for (int j = 0; j < 4; ++j) {
            float v = acc[i][j] + bia[j];
            o[j] = (mode == 1) ? tanhf(v) : v;
        }
        *(float4*)&C[(size_t)(m0 + tm * 4 + i) * N + n0 + tn * 4] = *(float4*)o;
    }
}

// ---------------------------------------------------------------------------
// Softmax over groups of 16 (axis = NL*NPT). One group per thread.
// total groups = BQ * NH = 348160 ; grid 1360 x 256
// ---------------------------------------------------------------------------
__global__ __launch_bounds__(256) void softmax16_kernel(
    const float* __restrict__ raw, float* __restrict__ out)
{
    int g = blockIdx.x * 256 + threadIdx.x;
    const float4* p = (const float4*)(raw + (size_t)g * 16);
    float4 t0 = p[0], t1 = p[1], t2 = p[2], t3 = p[3];
    float v[16] = {t0.x, t0.y, t0.z, t0.w, t1.x, t1.y, t1.z, t1.w,
                   t2.x, t2.y, t2.z, t2.w, t3.x, t3.y, t3.z, t3.w};
    float m = v[0];
#pragma unroll
    for (int k = 1; k < 16; ++k) m = fmaxf(m, v[k]);
    float s = 0.0f;
#pragma unroll
    for (int k = 0; k < 16; ++k) { v[k] = expf(v[k] - m); s += v[k]; }
    float inv = 1.0f / s;
    float4* o = (float4*)(out + (size_t)g * 16);
    o[0] = make_float4(v[0] * inv, v[1] * inv, v[2] * inv, v[3] * inv);
    o[1] = make_float4(v[4] * inv, v[5] * inv, v[6] * inv, v[7] * inv);
    o[2] = make_float4(v[8] * inv, v[9] * inv, v[10] * inv, v[11] * inv);
    o[3] = make_float4(v[12] * inv, v[13] * inv, v[14] * inv, v[15] * inv);
}

// ---------------------------------------------------------------------------
// Deformable sampling + aggregation. One block per (b,q).
// Threads 0..127 precompute (h,lvl,p) corner indices+weights into LDS.
// Then thread (h = tid>>5, c = tid&31) accumulates 16 points x 4 corners.
// NOTE: `offsets` and `agg` may alias (all offset reads complete before the
// barrier; agg writes happen after).
// ---------------------------------------------------------------------------
__global__ __launch_bounds__(256) void sample_kernel(
    const float* offsets,
    const float* __restrict__ attnw,
    const float* __restrict__ refp,
    const __hip_bfloat16* __restrict__ ft,
    float* agg)
{
    __shared__ int   sI[128][4];
    __shared__ float sWt[128][4];
    int bq = blockIdx.x;
    int tid = threadIdx.x;
    if (tid < 128) {
        int h = tid >> 4;
        int lvl = (tid >> 2) & 3;
        float2 off = *(const float2*)&offsets[(size_t)bq * 256 + tid * 2];
        float aw = attnw[(size_t)bq * 128 + tid];
        float2 rp = *(const float2*)&refp[(size_t)bq * 2];
        int b = bq / Qn;
        int Wl = 128 >> lvl;                              // H == W per level
        int base = (65536 - (65536 >> (2 * lvl))) / 3;
        float x = (rp.x + 0.5f * off.x) * (float)(Wl - 1);
        float y = (rp.y + 0.5f * off.y) * (float)(Wl - 1);
        float xf = floorf(x), yf = floorf(y);
        int x0 = (int)xf, y0 = (int)yf;
        int x1 = x0 + 1, y1 = y0 + 1;
        float wx1 = x - xf, wx0 = 1.0f - wx1;
        float wy1 = y - yf, wy0 = 1.0f - wy1;
        float vx0 = (x0 >= 0 && x0 < Wl) ? 1.0f : 0.0f;
        float vx1 = (x1 >= 0 && x1 < Wl) ? 1.0f : 0.0f;
        float vy0 = (y0 >= 0 && y0 < Wl) ? 1.0f : 0.0f;
        float vy1 = (y1 >= 0 && y1 < Wl) ? 1.0f : 0.0f;
        int xc0 = min(max(x0, 0), Wl - 1), xc1 = min(max(x1, 0), Wl - 1);
        int yc0 = min(max(y0, 0), Wl - 1), yc1 = min(max(y1, 0), Wl - 1);
        int sb = b * HWSUM + base;
        int hoff = h * 32;
        sI[tid][0] = (sb + yc0 * Wl + xc0) * 256 + hoff;
        sI[tid][1] = (sb + yc0 * Wl + xc1) * 256 + hoff;
        sI[tid][2] = (sb + yc1 * Wl + xc0) * 256 + hoff;
        sI[tid][3] = (sb + yc1 * Wl + xc1) * 256 + hoff;
        sWt[tid][0] = wx0 * wy0 * vx0 * vy0 * aw;
        sWt[tid][1] = wx1 * wy0 * vx1 * vy0 * aw;
        sWt[tid][2] = wx0 * wy1 * vx0 * vy1 * aw;
        sWt[tid][3] = wx1 * wy1 * vx1 * vy1 * aw;
    }
    __syncthreads();
    int h = tid >> 5, c = tid & 31;
    float acc = 0.0f;
#pragma unroll
    for (int j = 0; j < 16; ++j) {
        int it = h * 16 + j;
        float w0 = sWt[it][0], w1 = sWt[it][1], w2 = sWt[it][2], w3 = sWt[it][3];
        int i0 = sI[it][0], i1 = sI[it][1], i2 = sI[it][2], i3 = sI[it][3];
        acc += w0 * __bfloat162float(ft[i0 + c]);
        acc += w1 * __bfloat162float(ft[i1 + c]);
        acc += w2 * __bfloat162float(ft[i2 + c]);
        acc += w3 * __bfloat162float(ft[i3 + c]);
    }
    agg[(size_t)bq * 256 + tid] = acc;
}

// ---------------------------------------------------------------------------
extern "C" void kernel_launch(void* const* d_in, const int* in_sizes, int n_in,
                              void* d_out, int out_size, void* d_ws, size_t ws_size,
                              hipStream_t stream)
{
    const float* query  = (const float*)d_in[0];
    const float* f0     = (const float*)d_in[1];
    const float* f1     = (const float*)d_in[2];
    const float* f2     = (const float*)d_in[3];
    const float* f3     = (const float*)d_in[4];
    const float* refp   = (const float*)d_in[5];
    const float* W_off  = (const float*)d_in[6];
    const float* b_off  = (const float*)d_in[7];
    const float* W_attn = (const float*)d_in[8];
    const float* b_attn = (const float*)d_in[9];
    const float* W_out  = (const float*)d_in[10];
    const float* b_out  = (const float*)d_in[11];

    float* out      = (float*)d_out;                       // (B,Q,256)
    float* attn_out = out + (size_t)BQ * 256;              // (B,Q,8,4,4)

    // Workspace layout (floats):
    //   [0, 11141120)              offsets (B,Q,256)  -- later reused as agg
    //   [11141120, 16711680)       raw attn scores (B,Q,128)
    //   [16711680, +11141120 bf16) transposed feats (B, HWSUM, 256) bf16
    float* ws      = (float*)d_ws;
    float* offs    = ws;
    float* raw2    = ws + (size_t)11141120;
    __hip_bfloat16* ft = (__hip_bfloat16*)(ws + (size_t)16711680);
    float* agg     = offs;   // aliased with offsets (safe: see sample_kernel)

    feat_transpose_kernel<<<dim3(1360, 8), 256, 0, stream>>>(f0, f1, f2, f3, ft);
    gemm_kernel<<<dim3(680, 4), 256, 0, stream>>>(query, W_off, b_off, offs, 256, 1);
    gemm_kernel<<<dim3(680, 2), 256, 0, stream>>>(query, W_attn, b_attn, raw2, 128, 0);
    softmax16_kernel<<<dim3(1360), 256, 0, stream>>>(raw2, attn_out);
    sample_kernel<<<dim3(BQ), 256, 0, stream>>>(offs, attn_out, refp, ft, agg);
    gemm_kernel<<<dim3(680, 4), 256, 0, stream>>>(agg, W_out, b_out, out, 256, 0);
}

// Round 2
// 261.620 us; speedup vs baseline: 1.4431x; 1.4431x over previous
//
#include <hip/hip_runtime.h>
#include <hip/hip_bf16.h>

// Problem constants
#define Bn 2
#define Qn 21760
#define BQ 43520        // Bn*Qn
#define Dn 256
#define NHn 8
#define HDn 32
#define HWSUM 21760     // 128^2 + 64^2 + 32^2 + 16^2

typedef __attribute__((ext_vector_type(8))) short bf16x8;
typedef __attribute__((ext_vector_type(4))) float f32x4;

__device__ __forceinline__ unsigned short f2bf(float f) {
    __hip_bfloat16 h = __float2bfloat16(f);
    return __builtin_bit_cast(unsigned short, h);
}
__device__ __forceinline__ float bf2f(unsigned short u) {
    return __uint_as_float(((unsigned)u) << 16);
}
__device__ __forceinline__ void async16(const void* g, void* l) {
    __builtin_amdgcn_global_load_lds(
        (const __attribute__((address_space(1))) unsigned int*)g,
        (__attribute__((address_space(3))) unsigned int*)l, 16, 0, 0);
}

// ---------------------------------------------------------------------------
// Transpose feats (B, C=256, H, W) fp32 -> (B, pos, C) bf16, levels concat.
// grid: (1360, 8), block 256
// ---------------------------------------------------------------------------
__global__ __launch_bounds__(256) void feat_transpose_kernel(
    const float* __restrict__ f0, const float* __restrict__ f1,
    const float* __restrict__ f2, const float* __restrict__ f3,
    unsigned short* __restrict__ ft)
{
    __shared__ float tile[32][33];
    int bidx = blockIdx.x;
    int b = bidx / 680;
    int pos0 = (bidx - b * 680) * 32;
    int c0 = blockIdx.y * 32;
    int lvl = (pos0 >= 21504) ? 3 : (pos0 >= 20480) ? 2 : (pos0 >= 16384) ? 1 : 0;
    int HW = 16384 >> (2 * lvl);
    int base = (65536 - (65536 >> (2 * lvl))) / 3;   // 0,16384,20480,21504
    const float* f = (lvl == 0) ? f0 : (lvl == 1) ? f1 : (lvl == 2) ? f2 : f3;
    const float* src = f + (size_t)(b * 256 + c0) * HW + (pos0 - base);
    int tx = threadIdx.x & 31, ty = threadIdx.x >> 5;
#pragma unroll
    for (int cc = ty; cc < 32; cc += 8)
        tile[cc][tx] = src[(size_t)cc * HW + tx];
    __syncthreads();
#pragma unroll
    for (int ii = ty; ii < 32; ii += 8) {
        unsigned short* dst = ft + (size_t)(b * HWSUM + pos0 + ii) * 256 + c0;
        dst[tx] = f2bf(tile[tx][ii]);
    }
}

// ---------------------------------------------------------------------------
// Split query fp32 -> bf16 hi + bf16 lo (residual). Grid-stride, float4.
// ---------------------------------------------------------------------------
__global__ __launch_bounds__(256) void split_query_kernel(
    const float* __restrict__ q, unsigned short* __restrict__ hi,
    unsigned short* __restrict__ lo)
{
    size_t total = (size_t)BQ * 256;
    size_t stride = (size_t)gridDim.x * 256 * 4;
    for (size_t i = ((size_t)blockIdx.x * 256 + threadIdx.x) * 4; i < total; i += stride) {
        float4 v = *(const float4*)(q + i);
        ushort4 h, l;
        h.x = f2bf(v.x); l.x = f2bf(v.x - bf2f(h.x));
        h.y = f2bf(v.y); l.y = f2bf(v.y - bf2f(h.y));
        h.z = f2bf(v.z); l.z = f2bf(v.z - bf2f(h.z));
        h.w = f2bf(v.w); l.w = f2bf(v.w - bf2f(h.w));
        *(ushort4*)(hi + i) = h;
        *(ushort4*)(lo + i) = l;
    }
}

// ---------------------------------------------------------------------------
// Weight split+transpose: W[256][N] fp32 -> Bt_hi[N][256] bf16 (+ Bt_lo).
// grid (N/32, 8), block 256.
// ---------------------------------------------------------------------------
__global__ __launch_bounds__(256) void wsplit_kernel(
    const float* __restrict__ W, unsigned short* __restrict__ bthi,
    unsigned short* __restrict__ btlo, int N, int dolo)
{
    __shared__ float tile[32][33];
    int n0 = blockIdx.x * 32, k0 = blockIdx.y * 32;
    int tx = threadIdx.x & 31, ty = threadIdx.x >> 5;
#pragma unroll
    for (int r = ty; r < 32; r += 8)
        tile[r][tx] = W[(size_t)(k0 + r) * N + n0 + tx];
    __syncthreads();
#pragma unroll
    for (int r = ty; r < 32; r += 8) {
        float v = tile[tx][r];                 // W[k0+tx][n0+r]
        unsigned short h = f2bf(v);
        bthi[(size_t)(n0 + r) * 256 + k0 + tx] = h;
        if (dolo) btlo[(size_t)(n0 + r) * 256 + k0 + tx] = f2bf(v - bf2f(h));
    }
}

// ---------------------------------------------------------------------------
// bf16 MFMA GEMM: C[M,N] = A[M,256] @ Bt[N,256]^T + bias, fp32 out.
// 128x128 tile, BK=32, 4 waves (2x2), 16x16x32 MFMA. m97 structure.
// npasses=3 -> split-precision: (Ahi,Bhi)+(Alo,Bhi)+(Ahi,Blo).
// mode 1 -> tanh epilogue.
// ---------------------------------------------------------------------------
__global__ __launch_bounds__(256) void mfma_gemm(
    const unsigned short* __restrict__ Ahi, const unsigned short* __restrict__ Alo,
    const unsigned short* __restrict__ Bhi, const unsigned short* __restrict__ Blo,
    const float* __restrict__ bias, float* __restrict__ C,
    int N, int npasses, int mode)
{
    __shared__ unsigned short As[128 * 32];
    __shared__ unsigned short Bs[128 * 32];
    int tid = threadIdx.x;
    int m0 = blockIdx.x * 128, n0 = blockIdx.y * 128;
    int wave = tid >> 6, lane = tid & 63;
    int wr = wave >> 1, wc = wave & 1;
    int lr = lane & 15, kb = (lane >> 4) * 8;
    int arow = tid >> 2, aseg = (tid & 3) * 8;

    f32x4 acc[4][4] = {};

    for (int p = 0; p < npasses; ++p) {
        const unsigned short* Ap = (p == 1) ? Alo : Ahi;
        const unsigned short* Bp = (p == 2) ? Blo : Bhi;
        const unsigned short* Ag = Ap + (size_t)(m0 + arow) * 256 + aseg;
        const unsigned short* Bg = Bp + (size_t)(n0 + arow) * 256 + aseg;
        for (int kt = 0; kt < 256; kt += 32) {
            async16(Ag + kt,             &As[tid * 8]);
            async16(Ag + 64 * 256 + kt,  &As[tid * 8 + 2048]);
            async16(Bg + kt,             &Bs[tid * 8]);
            async16(Bg + 64 * 256 + kt,  &Bs[tid * 8 + 2048]);
            __syncthreads();
            bf16x8 af[4], bfr[4];
#pragma unroll
            for (int i = 0; i < 4; ++i) {
                af[i]  = *(const bf16x8*)&As[(wr * 64 + i * 16 + lr) * 32 + kb];
                bfr[i] = *(const bf16x8*)&Bs[(wc * 64 + i * 16 + lr) * 32 + kb];
            }
#pragma unroll
            for (int i = 0; i < 4; ++i)
#pragma unroll
                for (int j = 0; j < 4; ++j)
                    acc[i][j] = __builtin_amdgcn_mfma_f32_16x16x32_bf16(
                        af[i], bfr[j], acc[i][j], 0, 0, 0);
            __syncthreads();
        }
    }

    int crow = (lane >> 4) * 4;
#pragma unroll
    for (int j = 0; j < 4; ++j) {
        int gcol = n0 + wc * 64 + j * 16 + lr;
        float bv = bias[gcol];
#pragma unroll
        for (int i = 0; i < 4; ++i) {
            int grow = m0 + wr * 64 + i * 16 + crow;
#pragma unroll
            for (int r = 0; r < 4; ++r) {
                float v = acc[i][j][r] + bv;
                if (mode == 1) v = tanhf(v);
                C[(size_t)(grow + r) * N + gcol] = v;
            }
        }
    }
}

// ---------------------------------------------------------------------------
// Softmax over groups of 16. One group per thread. grid 1360 x 256.
// ---------------------------------------------------------------------------
__global__ __launch_bounds__(256) void softmax16_kernel(
    const float* __restrict__ raw, float* __restrict__ out)
{
    int g = blockIdx.x * 256 + threadIdx.x;
    const float4* p = (const float4*)(raw + (size_t)g * 16);
    float4 t0 = p[0], t1 = p[1], t2 = p[2], t3 = p[3];
    float v[16] = {t0.x, t0.y, t0.z, t0.w, t1.x, t1.y, t1.z, t1.w,
                   t2.x, t2.y, t2.z, t2.w, t3.x, t3.y, t3.z, t3.w};
    float m = v[0];
#pragma unroll
    for (int k = 1; k < 16; ++k) m = fmaxf(m, v[k]);
    float s = 0.0f;
#pragma unroll
    for (int k = 0; k < 16; ++k) { v[k] = expf(v[k] - m); s += v[k]; }
    float inv = 1.0f / s;
    float4* o = (float4*)(out + (size_t)g * 16);
    o[0] = make_float4(v[0] * inv, v[1] * inv, v[2] * inv, v[3] * inv);
    o[1] = make_float4(v[4] * inv, v[5] * inv, v[6] * inv, v[7] * inv);
    o[2] = make_float4(v[8] * inv, v[9] * inv, v[10] * inv, v[11] * inv);
    o[3] = make_float4(v[12] * inv, v[13] * inv, v[14] * inv, v[15] * inv);
}

// ---------------------------------------------------------------------------
// Deformable sampling + aggregation. Block = 4 queries x 64 threads.
// Wave = one query. Thread (qq, h = (t>>3)&7, c4 = (t&7)*4 channels).
// Per point-corner: dwordx2 gather (4 bf16 channels) + 4 FMA.
// Writes agg as bf16 (A-matrix of the output GEMM).
// ---------------------------------------------------------------------------
__global__ __launch_bounds__(256) void sample_kernel(
    const float* __restrict__ offs,
    const float* __restrict__ attnw,
    const float* __restrict__ refp,
    const unsigned short* __restrict__ ft,
    unsigned short* __restrict__ aggb)
{
    __shared__ int4   sI[512];
    __shared__ float4 sW[512];
    int tid = threadIdx.x;
    int bq0 = blockIdx.x * 4;

    for (int e = tid; e < 512; e += 256) {
        int qq = e >> 7;
        int pc = e & 127;                      // h*16 + lvl*4 + p
        int bq = bq0 + qq;
        int h = pc >> 4, lvl = (pc >> 2) & 3;
        float2 off = *(const float2*)&offs[((size_t)bq * 128 + pc) * 2];
        float aw = attnw[(size_t)bq * 128 + pc];
        float2 rp = *(const float2*)&refp[(size_t)bq * 2];
        int b = bq / Qn;
        int Wl = 128 >> lvl;
        int base = (lvl == 0) ? 0 : (lvl == 1) ? 16384 : (lvl == 2) ? 20480 : 21504;
        float x = (rp.x + 0.5f * off.x) * (float)(Wl - 1);
        float y = (rp.y + 0.5f * off.y) * (float)(Wl - 1);
        float xf = floorf(x), yf = floorf(y);
        int x0 = (int)xf, y0 = (int)yf;
        int x1 = x0 + 1, y1 = y0 + 1;
        float wx1 = x - xf, wx0 = 1.0f - wx1;
        float wy1 = y - yf, wy0 = 1.0f - wy1;
        float vx0 = (x0 >= 0 && x0 < Wl) ? 1.0f : 0.0f;
        float vx1 = (x1 >= 0 && x1 < Wl) ? 1.0f : 0.0f;
        float vy0 = (y0 >= 0 && y0 < Wl) ? 1.0f : 0.0f;
        float vy1 = (y1 >= 0 && y1 < Wl) ? 1.0f : 0.0f;
        int xc0 = min(max(x0, 0), Wl - 1), xc1 = min(max(x1, 0), Wl - 1);
        int yc0 = min(max(y0, 0), Wl - 1), yc1 = min(max(y1, 0), Wl - 1);
        int sb = b * HWSUM + base;
        int hoff = h * 32;
        int es = e ^ h;                        // bank-conflict swizzle
        sI[es] = make_int4((sb + yc0 * Wl + xc0) * 256 + hoff,
                           (sb + yc0 * Wl + xc1) * 256 + hoff,
                           (sb + yc1 * Wl + xc0) * 256 + hoff,
                           (sb + yc1 * Wl + xc1) * 256 + hoff);
        sW[es] = make_float4(wx0 * wy0 * vx0 * vy0 * aw,
                             wx1 * wy0 * vx1 * vy0 * aw,
                             wx0 * wy1 * vx0 * vy1 * aw,
                             wx1 * wy1 * vx1 * vy1 * aw);
    }
    __syncthreads();

    int qq = tid >> 6;
    int h = (tid >> 3) & 7;
    int c4 = (tid & 7) << 2;
    const unsigned short* fb = ft + c4;
    float a0 = 0.0f, a1 = 0.0f, a2 = 0.0f, a3 = 0.0f;
    int ebase = qq * 128 + h * 16;
#pragma unroll 4
    for (int j = 0; j < 16; ++j) {
        int es = (ebase + j) ^ h;
        int4 I = sI[es];
        float4 Wv = sW[es];
        {
            uint2 d = *(const uint2*)(fb + I.x);
            a0 += Wv.x * __uint_as_float(d.x << 16);
            a1 += Wv.x * __uint_as_float(d.x & 0xffff0000u);
            a2 += Wv.x * __uint_as_float(d.y << 16);
            a3 += Wv.x * __uint_as_float(d.y & 0xffff0000u);
        }
        {
            uint2 d = *(const uint2*)(fb + I.y);
            a0 += Wv.y * __uint_as_float(d.x << 16);
            a1 += Wv.y * __uint_as_float(d.x & 0xffff0000u);
            a2 += Wv.y * __uint_as_float(d.y << 16);
            a3 += Wv.y * __uint_as_float(d.y & 0xffff0000u);
        }
        {
            uint2 d = *(const uint2*)(fb + I.z);
            a0 += Wv.z * __uint_as_float(d.x << 16);
            a1 += Wv.z * __uint_as_float(d.x & 0xffff0000u);
            a2 += Wv.z * __uint_as_float(d.y << 16);
            a3 += Wv.z * __uint_as_float(d.y & 0xffff0000u);
        }
        {
            uint2 d = *(const uint2*)(fb + I.w);
            a0 += Wv.w * __uint_as_float(d.x << 16);
            a1 += Wv.w * __uint_as_float(d.x & 0xffff0000u);
            a2 += Wv.w * __uint_as_float(d.y << 16);
            a3 += Wv.w * __uint_as_float(d.y & 0xffff0000u);
        }
    }
    int bq = bq0 + qq;
    ushort4 o;
    o.x = f2bf(a0); o.y = f2bf(a1); o.z = f2bf(a2); o.w = f2bf(a3);
    *(ushort4*)&aggb[(size_t)bq * 256 + h * 32 + c4] = o;
}

// ---------------------------------------------------------------------------
extern "C" void kernel_launch(void* const* d_in, const int* in_sizes, int n_in,
                              void* d_out, int out_size, void* d_ws, size_t ws_size,
                              hipStream_t stream)
{
    const float* query  = (const float*)d_in[0];
    const float* f0     = (const float*)d_in[1];
    const float* f1     = (const float*)d_in[2];
    const float* f2     = (const float*)d_in[3];
    const float* f3     = (const float*)d_in[4];
    const float* refp   = (const float*)d_in[5];
    const float* W_off  = (const float*)d_in[6];
    const float* b_off  = (const float*)d_in[7];
    const float* W_attn = (const float*)d_in[8];
    const float* b_attn = (const float*)d_in[9];
    const float* W_out  = (const float*)d_in[10];
    const float* b_out  = (const float*)d_in[11];

    float* out      = (float*)d_out;                       // (B,Q,256)
    float* attn_out = out + (size_t)BQ * 256;              // (B,Q,8,4,4)

    // Workspace layout (bytes):
    char* w = (char*)d_ws;
    float* offs          = (float*)(w + 0);                 // 44,564,480  fp32 offsets
    unsigned short* ft   = (unsigned short*)(w + 44564480); // 22,282,240  bf16 feats (B,pos,C)
    unsigned short* qhi  = (unsigned short*)(w + 66846720); // 22,282,240  query hi bf16
    unsigned short* qlo  = (unsigned short*)(w + 89128960); // 22,282,240  query lo bf16
    float* raw2          = (float*)(w + 89128960);          // aliases qlo (used after GEMM1)
    unsigned short* aggb = (unsigned short*)(w + 111411200);// 22,282,240  agg bf16
    unsigned short* wofh = (unsigned short*)(w + 133693440);// 131,072  W_off^T hi
    unsigned short* wofl = (unsigned short*)(w + 133824512);// 131,072  W_off^T lo
    unsigned short* watn = (unsigned short*)(w + 133955584);//  65,536  W_attn^T
    unsigned short* wout = (unsigned short*)(w + 134021120);// 131,072  W_out^T

    feat_transpose_kernel<<<dim3(1360, 8), 256, 0, stream>>>(f0, f1, f2, f3, ft);
    split_query_kernel<<<dim3(2048), 256, 0, stream>>>(query, qhi, qlo);
    wsplit_kernel<<<dim3(8, 8), 256, 0, stream>>>(W_off, wofh, wofl, 256, 1);
    wsplit_kernel<<<dim3(4, 8), 256, 0, stream>>>(W_attn, watn, watn, 128, 0);
    wsplit_kernel<<<dim3(8, 8), 256, 0, stream>>>(W_out, wout, wout, 256, 0);

    // offsets = tanh(q @ W_off + b_off), split-precision bf16x3
    mfma_gemm<<<dim3(340, 2), 256, 0, stream>>>(qhi, qlo, wofh, wofl, b_off, offs, 256, 3, 1);
    // attn scores (bf16), then softmax into attn output
    mfma_gemm<<<dim3(340, 1), 256, 0, stream>>>(qhi, qhi, watn, watn, b_attn, raw2, 128, 1, 0);
    softmax16_kernel<<<dim3(1360), 256, 0, stream>>>(raw2, attn_out);
    // sampling + aggregation -> agg bf16
    sample_kernel<<<dim3(10880), 256, 0, stream>>>(offs, attn_out, refp, ft, aggb);
    // out = agg @ W_out + b_out
    mfma_gemm<<<dim3(340, 2), 256, 0, stream>>>(aggb, aggb, wout, wout, b_out, out, 256, 1, 0);
}

// Round 3
// 203.992 us; speedup vs baseline: 1.8507x; 1.2825x over previous
//
#include <hip/hip_runtime.h>
#include <hip/hip_bf16.h>

// Problem constants
#define Bn 2
#define Qn 21760
#define BQ 43520        // Bn*Qn
#define HWSUM 21760     // 128^2 + 64^2 + 32^2 + 16^2

typedef __attribute__((ext_vector_type(8))) short bf16x8;
typedef __attribute__((ext_vector_type(4))) float f32x4;

static __device__ __forceinline__ unsigned short f2bf(float f) {
    __hip_bfloat16 h = __float2bfloat16(f);
    return __builtin_bit_cast(unsigned short, h);
}
static __device__ __forceinline__ float bf2f(unsigned short u) {
    return __uint_as_float(((unsigned)u) << 16);
}
static __device__ __forceinline__ void async16(const void* g, void* l) {
    __builtin_amdgcn_global_load_lds(
        (const __attribute__((address_space(1))) unsigned int*)g,
        (__attribute__((address_space(3))) unsigned int*)l, 16, 0, 0);
}

// ---------------------------------------------------------------------------
// Transpose feats (B, C=256, H, W) fp32 -> head-major (B, 8h, pos, 32ch) bf16.
// grid: (1360, 8 heads), block 256
// ---------------------------------------------------------------------------
__global__ __launch_bounds__(256) void feat_transpose_kernel(
    const float* __restrict__ f0, const float* __restrict__ f1,
    const float* __restrict__ f2, const float* __restrict__ f3,
    unsigned short* __restrict__ ft)
{
    __shared__ float tile[32][33];
    int bidx = blockIdx.x;
    int b = bidx / 680;
    int pos0 = (bidx - b * 680) * 32;
    int h = blockIdx.y;
    int c0 = h * 32;
    int lvl = (pos0 >= 21504) ? 3 : (pos0 >= 20480) ? 2 : (pos0 >= 16384) ? 1 : 0;
    int HW = 16384 >> (2 * lvl);
    int base = (lvl == 0) ? 0 : (lvl == 1) ? 16384 : (lvl == 2) ? 20480 : 21504;
    const float* f = (lvl == 0) ? f0 : (lvl == 1) ? f1 : (lvl == 2) ? f2 : f3;
    const float* src = f + (size_t)(b * 256 + c0) * HW + (pos0 - base);
    int tx = threadIdx.x & 31, ty = threadIdx.x >> 5;
#pragma unroll
    for (int cc = ty; cc < 32; cc += 8)
        tile[cc][tx] = src[(size_t)cc * HW + tx];
    __syncthreads();
    size_t slab = (size_t)(b * 8 + h) * HWSUM + pos0;
#pragma unroll
    for (int ii = ty; ii < 32; ii += 8)
        ft[(slab + ii) * 32 + tx] = f2bf(tile[tx][ii]);
}

// ---------------------------------------------------------------------------
// Query spatial bucketing: 16x16 Morton cells per batch -> 512 bins.
// ---------------------------------------------------------------------------
__global__ void zero_hist_kernel(int* hist) { hist[threadIdx.x] = 0; }

static __device__ __forceinline__ int bin_of(const float* refp, int q) {
    float rx = refp[(size_t)q * 2], ry = refp[(size_t)q * 2 + 1];
    int cx = (int)(rx * 16.0f); cx = min(max(cx, 0), 15);
    int cy = (int)(ry * 16.0f); cy = min(max(cy, 0), 15);
    int m = 0;
#pragma unroll
    for (int i = 0; i < 4; ++i)
        m |= (((cx >> i) & 1) << (2 * i)) | (((cy >> i) & 1) << (2 * i + 1));
    return ((q >= Qn) ? 256 : 0) + m;
}

__global__ __launch_bounds__(256) void hist_kernel(
    const float* __restrict__ refp, int* hist)
{
    int q = blockIdx.x * 256 + threadIdx.x;
    if (q < BQ) atomicAdd(&hist[bin_of(refp, q)], 1);
}

__global__ __launch_bounds__(512) void scan_kernel(
    const int* __restrict__ hist, int* cursor)
{
    __shared__ int s[512];
    int t = threadIdx.x;
    int v0 = hist[t];
    s[t] = v0;
    __syncthreads();
    for (int d = 1; d < 512; d <<= 1) {
        int v = (t >= d) ? s[t - d] : 0;
        __syncthreads();
        s[t] += v;
        __syncthreads();
    }
    cursor[t] = s[t] - v0;   // exclusive prefix
}

__global__ __launch_bounds__(256) void scatter_kernel(
    const float* __restrict__ refp, int* cursor, int* order)
{
    int q = blockIdx.x * 256 + threadIdx.x;
    if (q < BQ) {
        int idx = atomicAdd(&cursor[bin_of(refp, q)], 1);
        order[idx] = q;
    }
}

// ---------------------------------------------------------------------------
// Weight split+transpose: W[256][N] fp32 -> Bt_hi[N][256] bf16 (+ Bt_lo).
// ---------------------------------------------------------------------------
__global__ __launch_bounds__(256) void wsplit_kernel(
    const float* __restrict__ W, unsigned short* __restrict__ bthi,
    unsigned short* __restrict__ btlo, int N, int dolo)
{
    __shared__ float tile[32][33];
    int n0 = blockIdx.x * 32, k0 = blockIdx.y * 32;
    int tx = threadIdx.x & 31, ty = threadIdx.x >> 5;
#pragma unroll
    for (int r = ty; r < 32; r += 8)
        tile[r][tx] = W[(size_t)(k0 + r) * N + n0 + tx];
    __syncthreads();
#pragma unroll
    for (int r = ty; r < 32; r += 8) {
        float v = tile[tx][r];
        unsigned short h = f2bf(v);
        bthi[(size_t)(n0 + r) * 256 + k0 + tx] = h;
        if (dolo) btlo[(size_t)(n0 + r) * 256 + k0 + tx] = f2bf(v - bf2f(h));
    }
}

// ---------------------------------------------------------------------------
// Fused query projection: reads fp32 query once, converts to bf16 hi/lo in
// registers, computes offsets (split-precision, tanh) AND attn scores
// (+ in-register softmax over groups of 16). grid (340, 3):
//   y=0,1 -> offset col-halves (3-term MFMA), y=2 -> attn + softmax.
// ---------------------------------------------------------------------------
__global__ __launch_bounds__(256) void qproj_kernel(
    const float* __restrict__ A,
    const unsigned short* __restrict__ wofh, const unsigned short* __restrict__ wofl,
    const unsigned short* __restrict__ watn,
    const float* __restrict__ b_off, const float* __restrict__ b_attn,
    float* __restrict__ offs, float* __restrict__ attn_out)
{
    __shared__ unsigned short Ah[128 * 32], Al[128 * 32];
    __shared__ unsigned short Bh[128 * 32], Bl[128 * 32];
    int tid = threadIdx.x;
    int y = blockIdx.y;
    bool attn = (y == 2);
    int m0 = blockIdx.x * 128;
    const unsigned short* Bhsrc = attn ? watn : (wofh + (size_t)y * 128 * 256);
    const unsigned short* Blsrc = wofl + (size_t)(attn ? 0 : y) * 128 * 256;
    int wave = tid >> 6, lane = tid & 63;
    int wr = wave >> 1, wc = wave & 1;
    int lr = lane & 15, kb = (lane >> 4) * 8;
    int arow = tid >> 2, aseg = (tid & 3) * 8;   // B staging (bf16, async)
    int srow = tid >> 1, sseg = (tid & 1) * 16;  // A staging (fp32->bf16)
    const float* Ag = A + (size_t)(m0 + srow) * 256 + sseg;
    const unsigned short* Bg  = Bhsrc + (size_t)arow * 256 + aseg;
    const unsigned short* Bg2 = Blsrc + (size_t)arow * 256 + aseg;

    f32x4 acc[4][4] = {};

#define PKPAIR(F0, F1, HP, LP) { \
        unsigned short h0_ = f2bf(F0), h1_ = f2bf(F1); \
        HP = (unsigned)h0_ | ((unsigned)h1_ << 16); \
        LP = (unsigned)f2bf((F0) - bf2f(h0_)) | ((unsigned)f2bf((F1) - bf2f(h1_)) << 16); }

    for (int kt = 0; kt < 256; kt += 32) {
        async16(Bg + kt,            &Bh[tid * 8]);
        async16(Bg + 64 * 256 + kt, &Bh[tid * 8 + 2048]);
        if (!attn) {
            async16(Bg2 + kt,            &Bl[tid * 8]);
            async16(Bg2 + 64 * 256 + kt, &Bl[tid * 8 + 2048]);
        }
        float4 q0 = *(const float4*)(Ag + kt);
        float4 q1 = *(const float4*)(Ag + kt + 4);
        float4 q2 = *(const float4*)(Ag + kt + 8);
        float4 q3 = *(const float4*)(Ag + kt + 12);
        uint4 HP0, HP1, LP0, LP1;
        PKPAIR(q0.x, q0.y, HP0.x, LP0.x); PKPAIR(q0.z, q0.w, HP0.y, LP0.y);
        PKPAIR(q1.x, q1.y, HP0.z, LP0.z); PKPAIR(q1.z, q1.w, HP0.w, LP0.w);
        PKPAIR(q2.x, q2.y, HP1.x, LP1.x); PKPAIR(q2.z, q2.w, HP1.y, LP1.y);
        PKPAIR(q3.x, q3.y, HP1.z, LP1.z); PKPAIR(q3.z, q3.w, HP1.w, LP1.w);
        *(uint4*)&Ah[srow * 32 + sseg]     = HP0;
        *(uint4*)&Ah[srow * 32 + sseg + 8] = HP1;
        if (!attn) {
            *(uint4*)&Al[srow * 32 + sseg]     = LP0;
            *(uint4*)&Al[srow * 32 + sseg + 8] = LP1;
        }
        __syncthreads();
        bf16x8 fah[4], fal[4], fbh[4], fbl[4];
#pragma unroll
        for (int i = 0; i < 4; ++i) {
            fah[i] = *(const bf16x8*)&Ah[(wr * 64 + i * 16 + lr) * 32 + kb];
            fbh[i] = *(const bf16x8*)&Bh[(wc * 64 + i * 16 + lr) * 32 + kb];
        }
        if (!attn) {
#pragma unroll
            for (int i = 0; i < 4; ++i) {
                fal[i] = *(const bf16x8*)&Al[(wr * 64 + i * 16 + lr) * 32 + kb];
                fbl[i] = *(const bf16x8*)&Bl[(wc * 64 + i * 16 + lr) * 32 + kb];
            }
        }
#pragma unroll
        for (int i = 0; i < 4; ++i)
#pragma unroll
            for (int j = 0; j < 4; ++j) {
                acc[i][j] = __builtin_amdgcn_mfma_f32_16x16x32_bf16(
                    fah[i], fbh[j], acc[i][j], 0, 0, 0);
                if (!attn) {
                    acc[i][j] = __builtin_amdgcn_mfma_f32_16x16x32_bf16(
                        fal[i], fbh[j], acc[i][j], 0, 0, 0);
                    acc[i][j] = __builtin_amdgcn_mfma_f32_16x16x32_bf16(
                        fah[i], fbl[j], acc[i][j], 0, 0, 0);
                }
            }
        __syncthreads();
    }

    int crow = (lane >> 4) * 4;
    if (!attn) {
#pragma unroll
        for (int j = 0; j < 4; ++j) {
            int gcol = y * 128 + wc * 64 + j * 16 + lr;
            float bv = b_off[gcol];
#pragma unroll
            for (int i = 0; i < 4; ++i) {
                int grow = m0 + wr * 64 + i * 16 + crow;
#pragma unroll
                for (int r = 0; r < 4; ++r)
                    offs[(size_t)(grow + r) * 256 + gcol] = tanhf(acc[i][j][r] + bv);
            }
        }
    } else {
#pragma unroll
        for (int j = 0; j < 4; ++j) {
            int col = wc * 64 + j * 16 + lr;
            float bv = b_attn[col];
#pragma unroll
            for (int i = 0; i < 4; ++i) {
                int grow = m0 + wr * 64 + i * 16 + crow;
#pragma unroll
                for (int r = 0; r < 4; ++r) {
                    float v = acc[i][j][r] + bv;
                    float mx = v;
                    mx = fmaxf(mx, __shfl_xor(mx, 1));
                    mx = fmaxf(mx, __shfl_xor(mx, 2));
                    mx = fmaxf(mx, __shfl_xor(mx, 4));
                    mx = fmaxf(mx, __shfl_xor(mx, 8));
                    float e = expf(v - mx);
                    float s = e;
                    s += __shfl_xor(s, 1);
                    s += __shfl_xor(s, 2);
                    s += __shfl_xor(s, 4);
                    s += __shfl_xor(s, 8);
                    attn_out[(size_t)(grow + r) * 128 + col] = e / s;
                }
            }
        }
    }
}

// ---------------------------------------------------------------------------
// Deformable sampling. Block = 4 bucketed queries x 8 heads x 8 lanes.
// Head-major feat layout lets 8 lanes fetch both x-corners of one row as a
// contiguous 128B uint4 sweep; shfl_xor(.,4) merges the corner partials.
// XCD-chunked block swizzle keeps each XCD on a spatially local query strip.
// ---------------------------------------------------------------------------
__global__ __launch_bounds__(256) void sample_kernel(
    const float* __restrict__ offs, const float* __restrict__ attnw,
    const float* __restrict__ refp, const unsigned short* __restrict__ ft,
    const int* __restrict__ order, unsigned short* __restrict__ aggb)
{
    __shared__ int4   sI[512];
    __shared__ float4 sW[512];
    int tid = threadIdx.x;
    int bid = blockIdx.x;
    int obid = (bid & 7) * 1360 + (bid >> 3);   // XCD-chunked swizzle (10880 = 8*1360)

#pragma unroll
    for (int e = tid; e < 512; e += 256) {
        int qq = e >> 7, pc = e & 127;
        int bq = order[obid * 4 + qq];
        int h = pc >> 4, lvl = (pc >> 2) & 3;
        float2 off = *(const float2*)&offs[((size_t)bq * 128 + pc) * 2];
        float aw = attnw[(size_t)bq * 128 + pc];
        float2 rp = *(const float2*)&refp[(size_t)bq * 2];
        int b = (bq >= Qn) ? 1 : 0;
        int Wl = 128 >> lvl;
        int base = (lvl == 0) ? 0 : (lvl == 1) ? 16384 : (lvl == 2) ? 20480 : 21504;
        float x = (rp.x + 0.5f * off.x) * (float)(Wl - 1);
        float y = (rp.y + 0.5f * off.y) * (float)(Wl - 1);
        float xf = floorf(x), yf = floorf(y);
        int x0 = (int)xf, y0 = (int)yf;
        float wx1 = x - xf, wx0 = 1.0f - wx1;
        float wy1 = y - yf, wy0 = 1.0f - wy1;
        float vx0 = (x0 >= 0 && x0 < Wl) ? 1.0f : 0.0f;
        float vx1 = (x0 + 1 >= 0 && x0 + 1 < Wl) ? 1.0f : 0.0f;
        float vy0 = (y0 >= 0 && y0 < Wl) ? 1.0f : 0.0f;
        float vy1 = (y0 + 1 >= 0 && y0 + 1 < Wl) ? 1.0f : 0.0f;
        int xc0 = min(max(x0, 0), Wl - 1), xc1 = min(max(x0 + 1, 0), Wl - 1);
        int yc0 = min(max(y0, 0), Wl - 1), yc1 = min(max(y0 + 1, 0), Wl - 1);
        int slab = (b * 8 + h) * HWSUM + base;
        int es = e ^ h;                          // LDS bank swizzle
        sI[es] = make_int4((slab + yc0 * Wl + xc0) * 32,
                           (slab + yc1 * Wl + xc0) * 32,
                           (xc1 - xc0) * 32, 0);
        sW[es] = make_float4(wx0 * wy0 * vx0 * vy0 * aw,
                             wx1 * wy0 * vx1 * vy0 * aw,
                             wx0 * wy1 * vx0 * vy1 * aw,
                             wx1 * wy1 * vx1 * vy1 * aw);
    }
    __syncthreads();

    int qq = tid >> 6;
    int h = (tid >> 3) & 7;
    int l = tid & 7;
    int cl = (l & 3) * 8;
    bool hiLane = (l & 4) != 0;
    float a[8] = {};
    int ebase = qq * 128 + h * 16;
#pragma unroll
    for (int j = 0; j < 16; ++j) {
        int es = (ebase + j) ^ h;
        int4 I = sI[es];
        float4 Wv = sW[es];
        int xo = hiLane ? I.z : 0;
        float w0 = hiLane ? Wv.y : Wv.x;
        float w1 = hiLane ? Wv.w : Wv.z;
        uint4 d0 = *(const uint4*)(ft + I.x + xo + cl);
        uint4 d1 = *(const uint4*)(ft + I.y + xo + cl);
        a[0] += w0 * __uint_as_float(d0.x << 16);
        a[1] += w0 * __uint_as_float(d0.x & 0xffff0000u);
        a[2] += w0 * __uint_as_float(d0.y << 16);
        a[3] += w0 * __uint_as_float(d0.y & 0xffff0000u);
        a[4] += w0 * __uint_as_float(d0.z << 16);
        a[5] += w0 * __uint_as_float(d0.z & 0xffff0000u);
        a[6] += w0 * __uint_as_float(d0.w << 16);
        a[7] += w0 * __uint_as_float(d0.w & 0xffff0000u);
        a[0] += w1 * __uint_as_float(d1.x << 16);
        a[1] += w1 * __uint_as_float(d1.x & 0xffff0000u);
        a[2] += w1 * __uint_as_float(d1.y << 16);
        a[3] += w1 * __uint_as_float(d1.y & 0xffff0000u);
        a[4] += w1 * __uint_as_float(d1.z << 16);
        a[5] += w1 * __uint_as_float(d1.z & 0xffff0000u);
        a[6] += w1 * __uint_as_float(d1.w << 16);
        a[7] += w1 * __uint_as_float(d1.w & 0xffff0000u);
    }
#pragma unroll
    for (int k = 0; k < 8; ++k) a[k] += __shfl_xor(a[k], 4);
    if (!hiLane) {
        int bq = order[obid * 4 + qq];
        uint4 o;
        o.x = (unsigned)f2bf(a[0]) | ((unsigned)f2bf(a[1]) << 16);
        o.y = (unsigned)f2bf(a[2]) | ((unsigned)f2bf(a[3]) << 16);
        o.z = (unsigned)f2bf(a[4]) | ((unsigned)f2bf(a[5]) << 16);
        o.w = (unsigned)f2bf(a[6]) | ((unsigned)f2bf(a[7]) << 16);
        *(uint4*)&aggb[(size_t)bq * 256 + h * 32 + cl] = o;
    }
}

// ---------------------------------------------------------------------------
// bf16 MFMA GEMM for the output projection: C = A[M,256] @ Bt[N,256]^T + bias.
// ---------------------------------------------------------------------------
__global__ __launch_bounds__(256) void mfma_gemm(
    const unsigned short* __restrict__ Abf, const unsigned short* __restrict__ Bt,
    const float* __restrict__ bias, float* __restrict__ C, int N)
{
    __shared__ unsigned short As[128 * 32];
    __shared__ unsigned short Bs[128 * 32];
    int tid = threadIdx.x;
    int m0 = blockIdx.x * 128, n0 = blockIdx.y * 128;
    int wave = tid >> 6, lane = tid & 63;
    int wr = wave >> 1, wc = wave & 1;
    int lr = lane & 15, kb = (lane >> 4) * 8;
    int arow = tid >> 2, aseg = (tid & 3) * 8;
    const unsigned short* Ag = Abf + (size_t)(m0 + arow) * 256 + aseg;
    const unsigned short* Bg = Bt + (size_t)(n0 + arow) * 256 + aseg;
    f32x4 acc[4][4] = {};
    for (int kt = 0; kt < 256; kt += 32) {
        async16(Ag + kt,            &As[tid * 8]);
        async16(Ag + 64 * 256 + kt, &As[tid * 8 + 2048]);
        async16(Bg + kt,            &Bs[tid * 8]);
        async16(Bg + 64 * 256 + kt, &Bs[tid * 8 + 2048]);
        __syncthreads();
        bf16x8 af[4], bfr[4];
#pragma unroll
        for (int i = 0; i < 4; ++i) {
            af[i]  = *(const bf16x8*)&As[(wr * 64 + i * 16 + lr) * 32 + kb];
            bfr[i] = *(const bf16x8*)&Bs[(wc * 64 + i * 16 + lr) * 32 + kb];
        }
#pragma unroll
        for (int i = 0; i < 4; ++i)
#pragma unroll
            for (int j = 0; j < 4; ++j)
                acc[i][j] = __builtin_amdgcn_mfma_f32_16x16x32_bf16(
                    af[i], bfr[j], acc[i][j], 0, 0, 0);
        __syncthreads();
    }
    int crow = (lane >> 4) * 4;
#pragma unroll
    for (int j = 0; j < 4; ++j) {
        int gcol = n0 + wc * 64 + j * 16 + lr;
        float bv = bias[gcol];
#pragma unroll
        for (int i = 0; i < 4; ++i) {
            int grow = m0 + wr * 64 + i * 16 + crow;
#pragma unroll
            for (int r = 0; r < 4; ++r)
                C[(size_t)(grow + r) * N + gcol] = acc[i][j][r] + bv;
        }
    }
}

// ---------------------------------------------------------------------------
extern "C" void kernel_launch(void* const* d_in, const int* in_sizes, int n_in,
                              void* d_out, int out_size, void* d_ws, size_t ws_size,
                              hipStream_t stream)
{
    const float* query  = (const float*)d_in[0];
    const float* f0     = (const float*)d_in[1];
    const float* f1     = (const float*)d_in[2];
    const float* f2     = (const float*)d_in[3];
    const float* f3     = (const float*)d_in[4];
    const float* refp   = (const float*)d_in[5];
    const float* W_off  = (const float*)d_in[6];
    const float* b_off  = (const float*)d_in[7];
    const float* W_attn = (const float*)d_in[8];
    const float* b_attn = (const float*)d_in[9];
    const float* W_out  = (const float*)d_in[10];
    const float* b_out  = (const float*)d_in[11];

    float* out      = (float*)d_out;                       // (B,Q,256)
    float* attn_out = out + (size_t)BQ * 256;              // (B,Q,8,4,4)

    // Workspace layout (bytes):
    char* w = (char*)d_ws;
    float* offs          = (float*)(w + 0);                 // 44,564,480
    unsigned short* ft   = (unsigned short*)(w + 44564480); // 22,282,240
    unsigned short* aggb = (unsigned short*)(w + 66846720); // 22,282,240
    unsigned short* wofh = (unsigned short*)(w + 89128960); // 131,072
    unsigned short* wofl = (unsigned short*)(w + 89260032); // 131,072
    unsigned short* watn = (unsigned short*)(w + 89391104); //  65,536
    unsigned short* wout = (unsigned short*)(w + 89456640); // 131,072
    int* hist            = (int*)(w + 89587712);            //   2,048
    int* cursor          = (int*)(w + 89589760);            //   2,048
    int* order           = (int*)(w + 89591808);            // 174,080

    // query bucketing (independent chain)
    zero_hist_kernel<<<1, 512, 0, stream>>>(hist);
    hist_kernel<<<170, 256, 0, stream>>>(refp, hist);
    scan_kernel<<<1, 512, 0, stream>>>(hist, cursor);
    scatter_kernel<<<170, 256, 0, stream>>>(refp, cursor, order);

    feat_transpose_kernel<<<dim3(1360, 8), 256, 0, stream>>>(f0, f1, f2, f3, ft);
    wsplit_kernel<<<dim3(8, 8), 256, 0, stream>>>(W_off, wofh, wofl, 256, 1);
    wsplit_kernel<<<dim3(4, 8), 256, 0, stream>>>(W_attn, watn, watn, 128, 0);
    wsplit_kernel<<<dim3(8, 8), 256, 0, stream>>>(W_out, wout, wout, 256, 0);

    // fused: offsets (split-precision + tanh) + attn scores + softmax
    qproj_kernel<<<dim3(340, 3), 256, 0, stream>>>(
        query, wofh, wofl, watn, b_off, b_attn, offs, attn_out);

    // sampling + aggregation -> agg bf16
    sample_kernel<<<dim3(10880), 256, 0, stream>>>(
        offs, attn_out, refp, ft, order, aggb);

    // out = agg @ W_out + b_out
    mfma_gemm<<<dim3(340, 2), 256, 0, stream>>>(aggb, wout, b_out, out, 256);
}

// Round 4
// 192.788 us; speedup vs baseline: 1.9583x; 1.0581x over previous
//
#include <hip/hip_runtime.h>
#include <hip/hip_bf16.h>

// Problem constants
#define Bn 2
#define Qn 21760
#define BQ 43520        // Bn*Qn
#define HWSUM 21760     // 128^2 + 64^2 + 32^2 + 16^2

typedef __attribute__((ext_vector_type(8))) short bf16x8;
typedef __attribute__((ext_vector_type(4))) float f32x4;
typedef __attribute__((ext_vector_type(2))) float f32x2;

static __device__ __forceinline__ unsigned short f2bf(float f) {
    __hip_bfloat16 h = __float2bfloat16(f);
    return __builtin_bit_cast(unsigned short, h);
}
static __device__ __forceinline__ float bf2f(unsigned short u) {
    return __uint_as_float(((unsigned)u) << 16);
}
static __device__ __forceinline__ void async16(const void* g, void* l) {
    __builtin_amdgcn_global_load_lds(
        (const __attribute__((address_space(1))) unsigned int*)g,
        (__attribute__((address_space(3))) unsigned int*)l, 16, 0, 0);
}
// unpack one uint (2 packed bf16) -> f32x2
static __device__ __forceinline__ f32x2 up2(unsigned u) {
    uint2 t = make_uint2(u << 16, u & 0xffff0000u);
    return __builtin_bit_cast(f32x2, t);
}
static __device__ __forceinline__ f32x2 fma2(float w, f32x2 v, f32x2 a) {
    f32x2 wv = {w, w};
    return __builtin_elementwise_fma(wv, v, a);
}

#define PKPAIR(F0, F1, HP, LP) { \
        unsigned short h0_ = f2bf(F0), h1_ = f2bf(F1); \
        HP = (unsigned)h0_ | ((unsigned)h1_ << 16); \
        LP = (unsigned)f2bf((F0) - bf2f(h0_)) | ((unsigned)f2bf((F1) - bf2f(h1_)) << 16); }

// ---------------------------------------------------------------------------
// Transpose feats (B, C=256, H, W) fp32 -> head-major (B, 8h, pos, 32ch) bf16.
// grid: (1360, 8 heads), block 256
// ---------------------------------------------------------------------------
__global__ __launch_bounds__(256) void feat_transpose_kernel(
    const float* __restrict__ f0, const float* __restrict__ f1,
    const float* __restrict__ f2, const float* __restrict__ f3,
    unsigned short* __restrict__ ft)
{
    __shared__ float tile[32][33];
    int bidx = blockIdx.x;
    int b = bidx / 680;
    int pos0 = (bidx - b * 680) * 32;
    int h = blockIdx.y;
    int c0 = h * 32;
    int lvl = (pos0 >= 21504) ? 3 : (pos0 >= 20480) ? 2 : (pos0 >= 16384) ? 1 : 0;
    int HW = 16384 >> (2 * lvl);
    int base = (lvl == 0) ? 0 : (lvl == 1) ? 16384 : (lvl == 2) ? 20480 : 21504;
    const float* f = (lvl == 0) ? f0 : (lvl == 1) ? f1 : (lvl == 2) ? f2 : f3;
    const float* src = f + (size_t)(b * 256 + c0) * HW + (pos0 - base);
    int tx = threadIdx.x & 31, ty = threadIdx.x >> 5;
#pragma unroll
    for (int cc = ty; cc < 32; cc += 8)
        tile[cc][tx] = src[(size_t)cc * HW + tx];
    __syncthreads();
    size_t slab = (size_t)(b * 8 + h) * HWSUM + pos0;
#pragma unroll
    for (int ii = ty; ii < 32; ii += 8)
        ft[(slab + ii) * 32 + tx] = f2bf(tile[tx][ii]);
}

// ---------------------------------------------------------------------------
// Query spatial bucketing: 16x16 Morton cells per batch -> 512 bins.
// ---------------------------------------------------------------------------
__global__ void zero_hist_kernel(int* hist) { hist[threadIdx.x] = 0; }

static __device__ __forceinline__ int bin_of(const float* refp, int q) {
    float rx = refp[(size_t)q * 2], ry = refp[(size_t)q * 2 + 1];
    int cx = (int)(rx * 16.0f); cx = min(max(cx, 0), 15);
    int cy = (int)(ry * 16.0f); cy = min(max(cy, 0), 15);
    int m = 0;
#pragma unroll
    for (int i = 0; i < 4; ++i)
        m |= (((cx >> i) & 1) << (2 * i)) | (((cy >> i) & 1) << (2 * i + 1));
    return ((q >= Qn) ? 256 : 0) + m;
}

__global__ __launch_bounds__(256) void hist_kernel(
    const float* __restrict__ refp, int* hist)
{
    int q = blockIdx.x * 256 + threadIdx.x;
    if (q < BQ) atomicAdd(&hist[bin_of(refp, q)], 1);
}

__global__ __launch_bounds__(512) void scan_kernel(
    const int* __restrict__ hist, int* cursor)
{
    __shared__ int s[512];
    int t = threadIdx.x;
    int v0 = hist[t];
    s[t] = v0;
    __syncthreads();
    for (int d = 1; d < 512; d <<= 1) {
        int v = (t >= d) ? s[t - d] : 0;
        __syncthreads();
        s[t] += v;
        __syncthreads();
    }
    cursor[t] = s[t] - v0;   // exclusive prefix
}

__global__ __launch_bounds__(256) void scatter_kernel(
    const float* __restrict__ refp, int* cursor, int* order)
{
    int q = blockIdx.x * 256 + threadIdx.x;
    if (q < BQ) {
        int idx = atomicAdd(&cursor[bin_of(refp, q)], 1);
        order[idx] = q;
    }
}

// ---------------------------------------------------------------------------
// Weight split+transpose: W[256][N] fp32 -> Bt_hi[N][256] bf16 (+ Bt_lo).
// ---------------------------------------------------------------------------
__global__ __launch_bounds__(256) void wsplit_kernel(
    const float* __restrict__ W, unsigned short* __restrict__ bthi,
    unsigned short* __restrict__ btlo, int N, int dolo)
{
    __shared__ float tile[32][33];
    int n0 = blockIdx.x * 32, k0 = blockIdx.y * 32;
    int tx = threadIdx.x & 31, ty = threadIdx.x >> 5;
#pragma unroll
    for (int r = ty; r < 32; r += 8)
        tile[r][tx] = W[(size_t)(k0 + r) * N + n0 + tx];
    __syncthreads();
#pragma unroll
    for (int r = ty; r < 32; r += 8) {
        float v = tile[tx][r];
        unsigned short h = f2bf(v);
        bthi[(size_t)(n0 + r) * 256 + k0 + tx] = h;
        if (dolo) btlo[(size_t)(n0 + r) * 256 + k0 + tx] = f2bf(v - bf2f(h));
    }
}

// ---------------------------------------------------------------------------
// Fused query projection, single pass over A. Block = 64 rows x 384 cols.
// Cols 0..255: offsets (split-precision 3-term MFMA + tanh).
// Cols 256..383: attn scores (1-term) + in-register softmax over 16-groups.
// Wave (2x2): wr rows-of-32, col blocks c16 = j*2+wc (j<8 -> offsets).
// grid 680, 4 waves, LDS 48KB, 3 blocks/CU.
// ---------------------------------------------------------------------------
__global__ __launch_bounds__(256, 3) void qproj_kernel(
    const float* __restrict__ A,
    const unsigned short* __restrict__ Wcat,   // [384][256] bf16 hi
    const unsigned short* __restrict__ Wlo,    // [256][256] bf16 lo (offset cols)
    const float* __restrict__ b_off, const float* __restrict__ b_attn,
    float* __restrict__ offs, float* __restrict__ attn_out)
{
    __shared__ unsigned short Ah[64 * 32], Al[64 * 32];
    __shared__ unsigned short Bh[384 * 32];
    __shared__ unsigned short Bl[256 * 32];
    int tid = threadIdx.x;
    int m0 = blockIdx.x * 64;
    int wave = tid >> 6, lane = tid & 63;
    int wr = wave >> 1, wc = wave & 1;
    int lr = lane & 15, kb = (lane >> 4) * 8;
    int srow = tid >> 2, sseg = (tid & 3) * 8;
    const float* Ag = A + (size_t)(m0 + srow) * 256 + sseg;

    f32x4 acc[2][12] = {};

    for (int kt = 0; kt < 256; kt += 32) {
        // B staging (async16, linear LDS)
#pragma unroll
        for (int p = 0; p < 6; ++p) {
            int tile = tid + p * 256;
            int row = tile >> 2, seg = tile & 3;
            async16(Wcat + (size_t)row * 256 + kt + seg * 8, &Bh[tile * 8]);
        }
#pragma unroll
        for (int p = 0; p < 4; ++p) {
            int tile = tid + p * 256;
            int row = tile >> 2, seg = tile & 3;
            async16(Wlo + (size_t)row * 256 + kt + seg * 8, &Bl[tile * 8]);
        }
        // A staging: fp32 -> bf16 hi/lo in registers
        float4 q0 = *(const float4*)(Ag + kt);
        float4 q1 = *(const float4*)(Ag + kt + 4);
        uint4 HP, LP;
        PKPAIR(q0.x, q0.y, HP.x, LP.x); PKPAIR(q0.z, q0.w, HP.y, LP.y);
        PKPAIR(q1.x, q1.y, HP.z, LP.z); PKPAIR(q1.z, q1.w, HP.w, LP.w);
        *(uint4*)&Ah[srow * 32 + sseg] = HP;
        *(uint4*)&Al[srow * 32 + sseg] = LP;
        __syncthreads();

        bf16x8 ah[2], al[2];
#pragma unroll
        for (int i = 0; i < 2; ++i) {
            ah[i] = *(const bf16x8*)&Ah[(wr * 32 + i * 16 + lr) * 32 + kb];
            al[i] = *(const bf16x8*)&Al[(wr * 32 + i * 16 + lr) * 32 + kb];
        }
#pragma unroll
        for (int j = 0; j < 12; ++j) {
            int c16 = j * 2 + wc;
            bf16x8 bh = *(const bf16x8*)&Bh[(c16 * 16 + lr) * 32 + kb];
            if (j < 8) {   // offset cols: 3-term split precision
                bf16x8 bl = *(const bf16x8*)&Bl[(c16 * 16 + lr) * 32 + kb];
#pragma unroll
                for (int i = 0; i < 2; ++i) {
                    acc[i][j] = __builtin_amdgcn_mfma_f32_16x16x32_bf16(ah[i], bh, acc[i][j], 0, 0, 0);
                    acc[i][j] = __builtin_amdgcn_mfma_f32_16x16x32_bf16(al[i], bh, acc[i][j], 0, 0, 0);
                    acc[i][j] = __builtin_amdgcn_mfma_f32_16x16x32_bf16(ah[i], bl, acc[i][j], 0, 0, 0);
                }
            } else {       // attn cols: 1-term
#pragma unroll
                for (int i = 0; i < 2; ++i)
                    acc[i][j] = __builtin_amdgcn_mfma_f32_16x16x32_bf16(ah[i], bh, acc[i][j], 0, 0, 0);
            }
        }
        __syncthreads();
    }

    int crow = (lane >> 4) * 4;
#pragma unroll
    for (int j = 0; j < 12; ++j) {
        int c16 = j * 2 + wc;
        if (j < 8) {
            int col = c16 * 16 + lr;
            float bv = b_off[col];
#pragma unroll
            for (int i = 0; i < 2; ++i) {
                int grow = m0 + wr * 32 + i * 16 + crow;
#pragma unroll
                for (int r = 0; r < 4; ++r)
                    offs[(size_t)(grow + r) * 256 + col] = tanhf(acc[i][j][r] + bv);
            }
        } else {
            int col = (c16 - 16) * 16 + lr;
            float bv = b_attn[col];
#pragma unroll
            for (int i = 0; i < 2; ++i) {
                int grow = m0 + wr * 32 + i * 16 + crow;
#pragma unroll
                for (int r = 0; r < 4; ++r) {
                    float v = acc[i][j][r] + bv;
                    float mx = v;
                    mx = fmaxf(mx, __shfl_xor(mx, 1));
                    mx = fmaxf(mx, __shfl_xor(mx, 2));
                    mx = fmaxf(mx, __shfl_xor(mx, 4));
                    mx = fmaxf(mx, __shfl_xor(mx, 8));
                    float e = expf(v - mx);
                    float s = e;
                    s += __shfl_xor(s, 1);
                    s += __shfl_xor(s, 2);
                    s += __shfl_xor(s, 4);
                    s += __shfl_xor(s, 8);
                    attn_out[(size_t)(grow + r) * 128 + col] = e / s;
                }
            }
        }
    }
}

// ---------------------------------------------------------------------------
// Deformable sampling. Block = 4 bucketed queries x 8 heads x 8 lanes.
// 3-slot software pipeline: corner-row loads issued 2 iterations ahead.
// Packed f32x2 unpack + v_pk_fma. sI holds BYTE offsets.
// ---------------------------------------------------------------------------
__global__ __launch_bounds__(256) void sample_kernel(
    const float* __restrict__ offs, const float* __restrict__ attnw,
    const float* __restrict__ refp, const unsigned short* __restrict__ ft,
    const int* __restrict__ order, unsigned short* __restrict__ aggb)
{
    __shared__ int4   sI[512];
    __shared__ float4 sW[512];
    int tid = threadIdx.x;
    int bid = blockIdx.x;
    int obid = (bid & 7) * 1360 + (bid >> 3);   // XCD-chunked swizzle

#pragma unroll
    for (int e = tid; e < 512; e += 256) {
        int qq = e >> 7, pc = e & 127;
        int bq = order[obid * 4 + qq];
        int h = pc >> 4, lvl = (pc >> 2) & 3;
        float2 off = *(const float2*)&offs[((size_t)bq * 128 + pc) * 2];
        float aw = attnw[(size_t)bq * 128 + pc];
        float2 rp = *(const float2*)&refp[(size_t)bq * 2];
        int b = (bq >= Qn) ? 1 : 0;
        int Wl = 128 >> lvl;
        int base = (lvl == 0) ? 0 : (lvl == 1) ? 16384 : (lvl == 2) ? 20480 : 21504;
        float x = (rp.x + 0.5f * off.x) * (float)(Wl - 1);
        float y = (rp.y + 0.5f * off.y) * (float)(Wl - 1);
        float xf = floorf(x), yf = floorf(y);
        int x0 = (int)xf, y0 = (int)yf;
        float wx1 = x - xf, wx0 = 1.0f - wx1;
        float wy1 = y - yf, wy0 = 1.0f - wy1;
        float vx0 = (x0 >= 0 && x0 < Wl) ? 1.0f : 0.0f;
        float vx1 = (x0 + 1 >= 0 && x0 + 1 < Wl) ? 1.0f : 0.0f;
        float vy0 = (y0 >= 0 && y0 < Wl) ? 1.0f : 0.0f;
        float vy1 = (y0 + 1 >= 0 && y0 + 1 < Wl) ? 1.0f : 0.0f;
        int xc0 = min(max(x0, 0), Wl - 1), xc1 = min(max(x0 + 1, 0), Wl - 1);
        int yc0 = min(max(y0, 0), Wl - 1), yc1 = min(max(y0 + 1, 0), Wl - 1);
        int slab = (b * 8 + h) * HWSUM + base;
        int es = e ^ h;                          // LDS bank swizzle
        sI[es] = make_int4((slab + yc0 * Wl + xc0) * 64,     // byte offsets
                           (slab + yc1 * Wl + xc0) * 64,
                           (xc1 - xc0) * 64, 0);
        sW[es] = make_float4(wx0 * wy0 * vx0 * vy0 * aw,
                             wx1 * wy0 * vx1 * vy0 * aw,
                             wx0 * wy1 * vx0 * vy1 * aw,
                             wx1 * wy1 * vx1 * vy1 * aw);
    }
    __syncthreads();

    int qq = tid >> 6;
    int h = (tid >> 3) & 7;
    int l = tid & 7;
    int cl2 = (l & 3) * 16;                  // byte offset within 32-ch row half
    bool hiLane = (l & 4) != 0;
    const char* fb = (const char*)ft;
    f32x2 a01 = {0.f, 0.f}, a23 = {0.f, 0.f}, a45 = {0.f, 0.f}, a67 = {0.f, 0.f};
    int ebase = qq * 128 + h * 16;

    uint4 dX[3], dY[3];
    float2 wv[3];

#define PREF(J, S) { \
        int es_ = (ebase + (J)) ^ h; \
        int4 I_ = sI[es_]; float4 Wf_ = sW[es_]; \
        int xo_ = (hiLane ? I_.z : 0) + cl2; \
        wv[S] = hiLane ? make_float2(Wf_.y, Wf_.w) : make_float2(Wf_.x, Wf_.z); \
        dX[S] = *(const uint4*)(fb + (size_t)(I_.x + xo_)); \
        dY[S] = *(const uint4*)(fb + (size_t)(I_.y + xo_)); }

    PREF(0, 0);
    PREF(1, 1);
#pragma unroll
    for (int j = 0; j < 16; ++j) {
        const int s = j % 3;
        if (j < 14) {
            const int s2 = (j + 2) % 3;
            PREF(j + 2, s2);
        }
        float w0 = wv[s].x, w1 = wv[s].y;
        uint4 d0 = dX[s], d1 = dY[s];
        a01 = fma2(w0, up2(d0.x), a01);
        a23 = fma2(w0, up2(d0.y), a23);
        a45 = fma2(w0, up2(d0.z), a45);
        a67 = fma2(w0, up2(d0.w), a67);
        a01 = fma2(w1, up2(d1.x), a01);
        a23 = fma2(w1, up2(d1.y), a23);
        a45 = fma2(w1, up2(d1.z), a45);
        a67 = fma2(w1, up2(d1.w), a67);
    }
#undef PREF

    float av[8] = {a01.x, a01.y, a23.x, a23.y, a45.x, a45.y, a67.x, a67.y};
#pragma unroll
    for (int k = 0; k < 8; ++k) av[k] += __shfl_xor(av[k], 4);
    if (!hiLane) {
        int bq = order[obid * 4 + qq];
        uint4 o;
        o.x = (unsigned)f2bf(av[0]) | ((unsigned)f2bf(av[1]) << 16);
        o.y = (unsigned)f2bf(av[2]) | ((unsigned)f2bf(av[3]) << 16);
        o.z = (unsigned)f2bf(av[4]) | ((unsigned)f2bf(av[5]) << 16);
        o.w = (unsigned)f2bf(av[6]) | ((unsigned)f2bf(av[7]) << 16);
        *(uint4*)&aggb[(size_t)bq * 256 + h * 32 + (l & 3) * 8] = o;
    }
}

// ---------------------------------------------------------------------------
// bf16 MFMA GEMM for the output projection: C = A[M,256] @ Bt[N,256]^T + bias.
// ---------------------------------------------------------------------------
__global__ __launch_bounds__(256) void mfma_gemm(
    const unsigned short* __restrict__ Abf, const unsigned short* __restrict__ Bt,
    const float* __restrict__ bias, float* __restrict__ C, int N)
{
    __shared__ unsigned short As[128 * 32];
    __shared__ unsigned short Bs[128 * 32];
    int tid = threadIdx.x;
    int m0 = blockIdx.x * 128, n0 = blockIdx.y * 128;
    int wave = tid >> 6, lane = tid & 63;
    int wr = wave >> 1, wc = wave & 1;
    int lr = lane & 15, kb = (lane >> 4) * 8;
    int arow = tid >> 2, aseg = (tid & 3) * 8;
    const unsigned short* Ag = Abf + (size_t)(m0 + arow) * 256 + aseg;
    const unsigned short* Bg = Bt + (size_t)(n0 + arow) * 256 + aseg;
    f32x4 acc[4][4] = {};
    for (int kt = 0; kt < 256; kt += 32) {
        async16(Ag + kt,            &As[tid * 8]);
        async16(Ag + 64 * 256 + kt, &As[tid * 8 + 2048]);
        async16(Bg + kt,            &Bs[tid * 8]);
        async16(Bg + 64 * 256 + kt, &Bs[tid * 8 + 2048]);
        __syncthreads();
        bf16x8 af[4], bfr[4];
#pragma unroll
        for (int i = 0; i < 4; ++i) {
            af[i]  = *(const bf16x8*)&As[(wr * 64 + i * 16 + lr) * 32 + kb];
            bfr[i] = *(const bf16x8*)&Bs[(wc * 64 + i * 16 + lr) * 32 + kb];
        }
#pragma unroll
        for (int i = 0; i < 4; ++i)
#pragma unroll
            for (int j = 0; j < 4; ++j)
                acc[i][j] = __builtin_amdgcn_mfma_f32_16x16x32_bf16(
                    af[i], bfr[j], acc[i][j], 0, 0, 0);
        __syncthreads();
    }
    int crow = (lane >> 4) * 4;
#pragma unroll
    for (int j = 0; j < 4; ++j) {
        int gcol = n0 + wc * 64 + j * 16 + lr;
        float bv = bias[gcol];
#pragma unroll
        for (int i = 0; i < 4; ++i) {
            int grow = m0 + wr * 64 + i * 16 + crow;
#pragma unroll
            for (int r = 0; r < 4; ++r)
                C[(size_t)(grow + r) * N + gcol] = acc[i][j][r] + bv;
        }
    }
}

// ---------------------------------------------------------------------------
extern "C" void kernel_launch(void* const* d_in, const int* in_sizes, int n_in,
                              void* d_out, int out_size, void* d_ws, size_t ws_size,
                              hipStream_t stream)
{
    const float* query  = (const float*)d_in[0];
    const float* f0     = (const float*)d_in[1];
    const float* f1     = (const float*)d_in[2];
    const float* f2     = (const float*)d_in[3];
    const float* f3     = (const float*)d_in[4];
    const float* refp   = (const float*)d_in[5];
    const float* W_off  = (const float*)d_in[6];
    const float* b_off  = (const float*)d_in[7];
    const float* W_attn = (const float*)d_in[8];
    const float* b_attn = (const float*)d_in[9];
    const float* W_out  = (const float*)d_in[10];
    const float* b_out  = (const float*)d_in[11];

    float* out      = (float*)d_out;                       // (B,Q,256)
    float* attn_out = out + (size_t)BQ * 256;              // (B,Q,8,4,4)

    // Workspace layout (bytes):
    char* w = (char*)d_ws;
    float* offs          = (float*)(w + 0);                 // 44,564,480
    unsigned short* ft   = (unsigned short*)(w + 44564480); // 22,282,240
    unsigned short* aggb = (unsigned short*)(w + 66846720); // 22,282,240
    unsigned short* Wcat = (unsigned short*)(w + 89128960); // 196,608 [384][256] hi
    unsigned short* Wlo  = (unsigned short*)(w + 89325568); // 131,072 [256][256] lo
    unsigned short* wout = (unsigned short*)(w + 89456640); // 131,072
    int* hist            = (int*)(w + 89587712);            //   2,048
    int* cursor          = (int*)(w + 89589760);            //   2,048
    int* order           = (int*)(w + 89591808);            // 174,080

    // query bucketing (independent chain)
    zero_hist_kernel<<<1, 512, 0, stream>>>(hist);
    hist_kernel<<<170, 256, 0, stream>>>(refp, hist);
    scan_kernel<<<1, 512, 0, stream>>>(hist, cursor);
    scatter_kernel<<<170, 256, 0, stream>>>(refp, cursor, order);

    feat_transpose_kernel<<<dim3(1360, 8), 256, 0, stream>>>(f0, f1, f2, f3, ft);
    wsplit_kernel<<<dim3(8, 8), 256, 0, stream>>>(W_off, Wcat, Wlo, 256, 1);
    wsplit_kernel<<<dim3(4, 8), 256, 0, stream>>>(W_attn, Wcat + 256 * 256, Wlo, 128, 0);
    wsplit_kernel<<<dim3(8, 8), 256, 0, stream>>>(W_out, wout, wout, 256, 0);

    // fused: offsets (split-precision + tanh) + attn scores + softmax
    qproj_kernel<<<dim3(680), 256, 0, stream>>>(
        query, Wcat, Wlo, b_off, b_attn, offs, attn_out);

    // sampling + aggregation -> agg bf16
    sample_kernel<<<dim3(10880), 256, 0, stream>>>(
        offs, attn_out, refp, ft, order, aggb);

    // out = agg @ W_out + b_out
    mfma_gemm<<<dim3(340, 2), 256, 0, stream>>>(aggb, wout, b_out, out, 256);
}

// Round 6
// 192.050 us; speedup vs baseline: 1.9658x; 1.0038x over previous
//
#include <hip/hip_runtime.h>
#include <hip/hip_bf16.h>

// Problem constants
#define Bn 2
#define Qn 21760
#define BQ 43520        // Bn*Qn
#define HWSUM 21760     // 128^2 + 64^2 + 32^2 + 16^2

typedef __attribute__((ext_vector_type(8))) short bf16x8;
typedef __attribute__((ext_vector_type(4))) float f32x4;
typedef __attribute__((ext_vector_type(2))) float f32x2;

static __device__ __forceinline__ unsigned short f2bf(float f) {
    __hip_bfloat16 h = __float2bfloat16(f);
    return __builtin_bit_cast(unsigned short, h);
}
static __device__ __forceinline__ float bf2f(unsigned short u) {
    return __uint_as_float(((unsigned)u) << 16);
}
static __device__ __forceinline__ void async16(const void* g, void* l) {
    __builtin_amdgcn_global_load_lds(
        (const __attribute__((address_space(1))) unsigned int*)g,
        (__attribute__((address_space(3))) unsigned int*)l, 16, 0, 0);
}
// unpack one uint (2 packed bf16) -> f32x2
static __device__ __forceinline__ f32x2 up2(unsigned u) {
    uint2 t = make_uint2(u << 16, u & 0xffff0000u);
    return __builtin_bit_cast(f32x2, t);
}
static __device__ __forceinline__ f32x2 fma2(float s, f32x2 v, f32x2 a) {
    f32x2 sv = {s, s};
    return __builtin_elementwise_fma(sv, v, a);
}

#define PKPAIR(F0, F1, HP, LP) { \
        unsigned short h0_ = f2bf(F0), h1_ = f2bf(F1); \
        HP = (unsigned)h0_ | ((unsigned)h1_ << 16); \
        LP = (unsigned)f2bf((F0) - bf2f(h0_)) | ((unsigned)f2bf((F1) - bf2f(h1_)) << 16); }

// ---------------------------------------------------------------------------
// Transpose feats (B, C=256, H, W) fp32 -> head-major (B, 8h, pos, 32ch) bf16.
// grid: (1360, 8 heads), block 256
// ---------------------------------------------------------------------------
__global__ __launch_bounds__(256) void feat_transpose_kernel(
    const float* __restrict__ f0, const float* __restrict__ f1,
    const float* __restrict__ f2, const float* __restrict__ f3,
    unsigned short* __restrict__ ft)
{
    __shared__ float tile[32][33];
    int bidx = blockIdx.x;
    int b = bidx / 680;
    int pos0 = (bidx - b * 680) * 32;
    int h = blockIdx.y;
    int c0 = h * 32;
    int lvl = (pos0 >= 21504) ? 3 : (pos0 >= 20480) ? 2 : (pos0 >= 16384) ? 1 : 0;
    int HW = 16384 >> (2 * lvl);
    int base = (lvl == 0) ? 0 : (lvl == 1) ? 16384 : (lvl == 2) ? 20480 : 21504;
    const float* f = (lvl == 0) ? f0 : (lvl == 1) ? f1 : (lvl == 2) ? f2 : f3;
    const float* src = f + (size_t)(b * 256 + c0) * HW + (pos0 - base);
    int tx = threadIdx.x & 31, ty = threadIdx.x >> 5;
#pragma unroll
    for (int cc = ty; cc < 32; cc += 8)
        tile[cc][tx] = src[(size_t)cc * HW + tx];
    __syncthreads();
    size_t slab = (size_t)(b * 8 + h) * HWSUM + pos0;
#pragma unroll
    for (int ii = ty; ii < 32; ii += 8)
        ft[(slab + ii) * 32 + tx] = f2bf(tile[tx][ii]);
}

// ---------------------------------------------------------------------------
// Query spatial bucketing: 16x16 Morton cells per batch -> 512 bins.
// ---------------------------------------------------------------------------
__global__ void zero_hist_kernel(int* hist) { hist[threadIdx.x] = 0; }

static __device__ __forceinline__ int bin_of(const float* refp, int q) {
    float rx = refp[(size_t)q * 2], ry = refp[(size_t)q * 2 + 1];
    int cx = (int)(rx * 16.0f); cx = min(max(cx, 0), 15);
    int cy = (int)(ry * 16.0f); cy = min(max(cy, 0), 15);
    int m = 0;
#pragma unroll
    for (int i = 0; i < 4; ++i)
        m |= (((cx >> i) & 1) << (2 * i)) | (((cy >> i) & 1) << (2 * i + 1));
    return ((q >= Qn) ? 256 : 0) + m;
}

__global__ __launch_bounds__(256) void hist_kernel(
    const float* __restrict__ refp, int* hist)
{
    int q = blockIdx.x * 256 + threadIdx.x;
    if (q < BQ) atomicAdd(&hist[bin_of(refp, q)], 1);
}

__global__ __launch_bounds__(512) void scan_kernel(
    const int* __restrict__ hist, int* cursor)
{
    __shared__ int s[512];
    int t = threadIdx.x;
    int v0 = hist[t];
    s[t] = v0;
    __syncthreads();
    for (int d = 1; d < 512; d <<= 1) {
        int v = (t >= d) ? s[t - d] : 0;
        __syncthreads();
        s[t] += v;
        __syncthreads();
    }
    cursor[t] = s[t] - v0;   // exclusive prefix
}

__global__ __launch_bounds__(256) void scatter_kernel(
    const float* __restrict__ refp, int* cursor, int* order)
{
    int q = blockIdx.x * 256 + threadIdx.x;
    if (q < BQ) {
        int idx = atomicAdd(&cursor[bin_of(refp, q)], 1);
        order[idx] = q;
    }
}

// ---------------------------------------------------------------------------
// Weight split+transpose: W[256][N] fp32 -> Bt_hi[N][256] bf16 (+ Bt_lo).
// ---------------------------------------------------------------------------
__global__ __launch_bounds__(256) void wsplit_kernel(
    const float* __restrict__ W, unsigned short* __restrict__ bthi,
    unsigned short* __restrict__ btlo, int N, int dolo)
{
    __shared__ float tile[32][33];
    int n0 = blockIdx.x * 32, k0 = blockIdx.y * 32;
    int tx = threadIdx.x & 31, ty = threadIdx.x >> 5;
#pragma unroll
    for (int r = ty; r < 32; r += 8)
        tile[r][tx] = W[(size_t)(k0 + r) * N + n0 + tx];
    __syncthreads();
#pragma unroll
    for (int r = ty; r < 32; r += 8) {
        float v = tile[tx][r];
        unsigned short h = f2bf(v);
        bthi[(size_t)(n0 + r) * 256 + k0 + tx] = h;
        if (dolo) btlo[(size_t)(n0 + r) * 256 + k0 + tx] = f2bf(v - bf2f(h));
    }
}

// ---------------------------------------------------------------------------
// Fused query projection, single pass over A. Block = 64 rows x 384 cols.
// Cols 0..255: offsets (split-precision 3-term MFMA + tanh).
// Cols 256..383: attn scores (1-term) + in-register softmax over 16-groups.
// ---------------------------------------------------------------------------
__global__ __launch_bounds__(256, 3) void qproj_kernel(
    const float* __restrict__ A,
    const unsigned short* __restrict__ Wcat,   // [384][256] bf16 hi
    const unsigned short* __restrict__ Wlo,    // [256][256] bf16 lo (offset cols)
    const float* __restrict__ b_off, const float* __restrict__ b_attn,
    float* __restrict__ offs, float* __restrict__ attn_out)
{
    __shared__ unsigned short Ah[64 * 32], Al[64 * 32];
    __shared__ unsigned short Bh[384 * 32];
    __shared__ unsigned short Bl[256 * 32];
    int tid = threadIdx.x;
    int m0 = blockIdx.x * 64;
    int wave = tid >> 6, lane = tid & 63;
    int wr = wave >> 1, wc = wave & 1;
    int lr = lane & 15, kb = (lane >> 4) * 8;
    int srow = tid >> 2, sseg = (tid & 3) * 8;
    const float* Ag = A + (size_t)(m0 + srow) * 256 + sseg;

    f32x4 acc[2][12] = {};

    for (int kt = 0; kt < 256; kt += 32) {
        // B staging (async16, linear LDS)
#pragma unroll
        for (int p = 0; p < 6; ++p) {
            int tile = tid + p * 256;
            int row = tile >> 2, seg = tile & 3;
            async16(Wcat + (size_t)row * 256 + kt + seg * 8, &Bh[tile * 8]);
        }
#pragma unroll
        for (int p = 0; p < 4; ++p) {
            int tile = tid + p * 256;
            int row = tile >> 2, seg = tile & 3;
            async16(Wlo + (size_t)row * 256 + kt + seg * 8, &Bl[tile * 8]);
        }
        // A staging: fp32 -> bf16 hi/lo in registers
        float4 q0 = *(const float4*)(Ag + kt);
        float4 q1 = *(const float4*)(Ag + kt + 4);
        uint4 HP, LP;
        PKPAIR(q0.x, q0.y, HP.x, LP.x); PKPAIR(q0.z, q0.w, HP.y, LP.y);
        PKPAIR(q1.x, q1.y, HP.z, LP.z); PKPAIR(q1.z, q1.w, HP.w, LP.w);
        *(uint4*)&Ah[srow * 32 + sseg] = HP;
        *(uint4*)&Al[srow * 32 + sseg] = LP;
        __syncthreads();

        bf16x8 ah[2], al[2];
#pragma unroll
        for (int i = 0; i < 2; ++i) {
            ah[i] = *(const bf16x8*)&Ah[(wr * 32 + i * 16 + lr) * 32 + kb];
            al[i] = *(const bf16x8*)&Al[(wr * 32 + i * 16 + lr) * 32 + kb];
        }
#pragma unroll
        for (int j = 0; j < 12; ++j) {
            int c16 = j * 2 + wc;
            bf16x8 bh = *(const bf16x8*)&Bh[(c16 * 16 + lr) * 32 + kb];
            if (j < 8) {   // offset cols: 3-term split precision
                bf16x8 bl = *(const bf16x8*)&Bl[(c16 * 16 + lr) * 32 + kb];
#pragma unroll
                for (int i = 0; i < 2; ++i) {
                    acc[i][j] = __builtin_amdgcn_mfma_f32_16x16x32_bf16(ah[i], bh, acc[i][j], 0, 0, 0);
                    acc[i][j] = __builtin_amdgcn_mfma_f32_16x16x32_bf16(al[i], bh, acc[i][j], 0, 0, 0);
                    acc[i][j] = __builtin_amdgcn_mfma_f32_16x16x32_bf16(ah[i], bl, acc[i][j], 0, 0, 0);
                }
            } else {       // attn cols: 1-term
#pragma unroll
                for (int i = 0; i < 2; ++i)
                    acc[i][j] = __builtin_amdgcn_mfma_f32_16x16x32_bf16(ah[i], bh, acc[i][j], 0, 0, 0);
            }
        }
        __syncthreads();
    }

    int crow = (lane >> 4) * 4;
#pragma unroll
    for (int j = 0; j < 12; ++j) {
        int c16 = j * 2 + wc;
        if (j < 8) {
            int col = c16 * 16 + lr;
            float bv = b_off[col];
#pragma unroll
            for (int i = 0; i < 2; ++i) {
                int grow = m0 + wr * 32 + i * 16 + crow;
#pragma unroll
                for (int r = 0; r < 4; ++r)
                    offs[(size_t)(grow + r) * 256 + col] = tanhf(acc[i][j][r] + bv);
            }
        } else {
            int col = (c16 - 16) * 16 + lr;
            float bv = b_attn[col];
#pragma unroll
            for (int i = 0; i < 2; ++i) {
                int grow = m0 + wr * 32 + i * 16 + crow;
#pragma unroll
                for (int r = 0; r < 4; ++r) {
                    float v = acc[i][j][r] + bv;
                    float mx = v;
                    mx = fmaxf(mx, __shfl_xor(mx, 1));
                    mx = fmaxf(mx, __shfl_xor(mx, 2));
                    mx = fmaxf(mx, __shfl_xor(mx, 4));
                    mx = fmaxf(mx, __shfl_xor(mx, 8));
                    float e = expf(v - mx);
                    float s = e;
                    s += __shfl_xor(s, 1);
                    s += __shfl_xor(s, 2);
                    s += __shfl_xor(s, 4);
                    s += __shfl_xor(s, 8);
                    attn_out[(size_t)(grow + r) * 128 + col] = e / s;
                }
            }
        }
    }
}

// ---------------------------------------------------------------------------
// Pipeline helpers for sample_kernel (inline fns, not macros — round-5 fix).
// After inlining + full unroll all array indices are literals -> registers.
// ---------------------------------------------------------------------------
static __device__ __forceinline__ void issue4(
    const int4* sIp, const float4* sWp, const char* fb,
    int ebase, int J, int h, int cl2, bool hiLane,
    uint4 (&dst)[8], float2 (&wt)[4])
{
#pragma unroll
    for (int t = 0; t < 4; ++t) {
        int es = (ebase + J + t) ^ h;
        int4 I = sIp[es];
        float4 Wf = sWp[es];
        int xo = (hiLane ? I.z : 0) + cl2;
        wt[t] = hiLane ? make_float2(Wf.y, Wf.w) : make_float2(Wf.x, Wf.z);
        dst[2 * t]     = *(const uint4*)(fb + (size_t)(unsigned)(I.x + xo));
        dst[2 * t + 1] = *(const uint4*)(fb + (size_t)(unsigned)(I.y + xo));
    }
}

static __device__ __forceinline__ void consume4(
    const uint4 (&src)[8], const float2 (&wt)[4],
    f32x2& a01, f32x2& a23, f32x2& a45, f32x2& a67)
{
#pragma unroll
    for (int t = 0; t < 4; ++t) {
        float s0 = wt[t].x, s1 = wt[t].y;
        uint4 d0 = src[2 * t], d1 = src[2 * t + 1];
        a01 = fma2(s0, up2(d0.x), a01);
        a23 = fma2(s0, up2(d0.y), a23);
        a45 = fma2(s0, up2(d0.z), a45);
        a67 = fma2(s0, up2(d0.w), a67);
        a01 = fma2(s1, up2(d1.x), a01);
        a23 = fma2(s1, up2(d1.y), a23);
        a45 = fma2(s1, up2(d1.z), a45);
        a67 = fma2(s1, up2(d1.w), a67);
    }
}

// ---------------------------------------------------------------------------
// Deformable sampling. Block = 4 bucketed queries x 8 heads x 8 lanes.
// Explicit 2-batch x 4-point ping-pong pipeline: 8 dwordx4 gathers issued per
// batch into named register slots; consume(A) overlaps flight-time of B.
// __launch_bounds__(256,4): 128-VGPR budget so the allocator KEEPS the
// pipeline (round-4 collapse: 32 VGPR = loads sunk to use).
// ---------------------------------------------------------------------------
__global__ __launch_bounds__(256, 4) void sample_kernel(
    const float* __restrict__ offs, const float* __restrict__ attnw,
    const float* __restrict__ refp, const unsigned short* __restrict__ ft,
    const int* __restrict__ order, unsigned short* __restrict__ aggb)
{
    __shared__ int4   sI[512];
    __shared__ float4 sW[512];
    int tid = threadIdx.x;
    int bid = blockIdx.x;
    int obid = (bid & 7) * 1360 + (bid >> 3);   // XCD-chunked swizzle

#pragma unroll
    for (int e = tid; e < 512; e += 256) {
        int qq = e >> 7, pc = e & 127;
        int bq = order[obid * 4 + qq];
        int h = pc >> 4, lvl = (pc >> 2) & 3;
        float2 off = *(const float2*)&offs[((size_t)bq * 128 + pc) * 2];
        float aw = attnw[(size_t)bq * 128 + pc];
        float2 rp = *(const float2*)&refp[(size_t)bq * 2];
        int b = (bq >= Qn) ? 1 : 0;
        int Wl = 128 >> lvl;
        int base = (lvl == 0) ? 0 : (lvl == 1) ? 16384 : (lvl == 2) ? 20480 : 21504;
        float x = (rp.x + 0.5f * off.x) * (float)(Wl - 1);
        float y = (rp.y + 0.5f * off.y) * (float)(Wl - 1);
        float xf = floorf(x), yf = floorf(y);
        int x0 = (int)xf, y0 = (int)yf;
        float wx1 = x - xf, wx0 = 1.0f - wx1;
        float wy1 = y - yf, wy0 = 1.0f - wy1;
        float vx0 = (x0 >= 0 && x0 < Wl) ? 1.0f : 0.0f;
        float vx1 = (x0 + 1 >= 0 && x0 + 1 < Wl) ? 1.0f : 0.0f;
        float vy0 = (y0 >= 0 && y0 < Wl) ? 1.0f : 0.0f;
        float vy1 = (y0 + 1 >= 0 && y0 + 1 < Wl) ? 1.0f : 0.0f;
        int xc0 = min(max(x0, 0), Wl - 1), xc1 = min(max(x0 + 1, 0), Wl - 1);
        int yc0 = min(max(y0, 0), Wl - 1), yc1 = min(max(y0 + 1, 0), Wl - 1);
        int slab = (b * 8 + h) * HWSUM + base;
        int es = e ^ h;                          // LDS bank swizzle
        sI[es] = make_int4((slab + yc0 * Wl + xc0) * 64,     // byte offsets
                           (slab + yc1 * Wl + xc0) * 64,
                           (xc1 - xc0) * 64, 0);
        sW[es] = make_float4(wx0 * wy0 * vx0 * vy0 * aw,
                             wx1 * wy0 * vx1 * vy0 * aw,
                             wx0 * wy1 * vx0 * vy1 * aw,
                             wx1 * wy1 * vx1 * vy1 * aw);
    }
    __syncthreads();

    int qq = tid >> 6;
    int h = (tid >> 3) & 7;
    int l = tid & 7;
    int cl2 = (l & 3) * 16;                  // byte offset within 32-ch row half
    bool hiLane = (l & 4) != 0;
    const char* fb = (const char*)ft;
    f32x2 a01 = {0.f, 0.f}, a23 = {0.f, 0.f}, a45 = {0.f, 0.f}, a67 = {0.f, 0.f};
    int ebase = qq * 128 + h * 16;

    uint4 dA[8]; float2 wA[4];
    uint4 dB[8]; float2 wB[4];

    issue4(sI, sW, fb, ebase, 0, h, cl2, hiLane, dA, wA);
    issue4(sI, sW, fb, ebase, 4, h, cl2, hiLane, dB, wB);
    consume4(dA, wA, a01, a23, a45, a67);
    issue4(sI, sW, fb, ebase, 8, h, cl2, hiLane, dA, wA);
    consume4(dB, wB, a01, a23, a45, a67);
    issue4(sI, sW, fb, ebase, 12, h, cl2, hiLane, dB, wB);
    consume4(dA, wA, a01, a23, a45, a67);
    consume4(dB, wB, a01, a23, a45, a67);

    float av[8] = {a01.x, a01.y, a23.x, a23.y, a45.x, a45.y, a67.x, a67.y};
#pragma unroll
    for (int k = 0; k < 8; ++k) av[k] += __shfl_xor(av[k], 4);
    if (!hiLane) {
        int bq = order[obid * 4 + qq];
        uint4 o;
        o.x = (unsigned)f2bf(av[0]) | ((unsigned)f2bf(av[1]) << 16);
        o.y = (unsigned)f2bf(av[2]) | ((unsigned)f2bf(av[3]) << 16);
        o.z = (unsigned)f2bf(av[4]) | ((unsigned)f2bf(av[5]) << 16);
        o.w = (unsigned)f2bf(av[6]) | ((unsigned)f2bf(av[7]) << 16);
        *(uint4*)&aggb[(size_t)bq * 256 + h * 32 + (l & 3) * 8] = o;
    }
}

// ---------------------------------------------------------------------------
// bf16 MFMA GEMM for the output projection: C = A[M,256] @ Bt[N,256]^T + bias.
// ---------------------------------------------------------------------------
__global__ __launch_bounds__(256) void mfma_gemm(
    const unsigned short* __restrict__ Abf, const unsigned short* __restrict__ Bt,
    const float* __restrict__ bias, float* __restrict__ C, int N)
{
    __shared__ unsigned short As[128 * 32];
    __shared__ unsigned short Bs[128 * 32];
    int tid = threadIdx.x;
    int m0 = blockIdx.x * 128, n0 = blockIdx.y * 128;
    int wave = tid >> 6, lane = tid & 63;
    int wr = wave >> 1, wc = wave & 1;
    int lr = lane & 15, kb = (lane >> 4) * 8;
    int arow = tid >> 2, aseg = (tid & 3) * 8;
    const unsigned short* Ag = Abf + (size_t)(m0 + arow) * 256 + aseg;
    const unsigned short* Bg = Bt + (size_t)(n0 + arow) * 256 + aseg;
    f32x4 acc[4][4] = {};
    for (int kt = 0; kt < 256; kt += 32) {
        async16(Ag + kt,            &As[tid * 8]);
        async16(Ag + 64 * 256 + kt, &As[tid * 8 + 2048]);
        async16(Bg + kt,            &Bs[tid * 8]);
        async16(Bg + 64 * 256 + kt, &Bs[tid * 8 + 2048]);
        __syncthreads();
        bf16x8 af[4], bfr[4];
#pragma unroll
        for (int i = 0; i < 4; ++i) {
            af[i]  = *(const bf16x8*)&As[(wr * 64 + i * 16 + lr) * 32 + kb];
            bfr[i] = *(const bf16x8*)&Bs[(wc * 64 + i * 16 + lr) * 32 + kb];
        }
#pragma unroll
        for (int i = 0; i < 4; ++i)
#pragma unroll
            for (int j = 0; j < 4; ++j)
                acc[i][j] = __builtin_amdgcn_mfma_f32_16x16x32_bf16(
                    af[i], bfr[j], acc[i][j], 0, 0, 0);
        __syncthreads();
    }
    int crow = (lane >> 4) * 4;
#pragma unroll
    for (int j = 0; j < 4; ++j) {
        int gcol = n0 + wc * 64 + j * 16 + lr;
        float bv = bias[gcol];
#pragma unroll
        for (int i = 0; i < 4; ++i) {
            int grow = m0 + wr * 64 + i * 16 + crow;
#pragma unroll
            for (int r = 0; r < 4; ++r)
                C[(size_t)(grow + r) * N + gcol] = acc[i][j][r] + bv;
        }
    }
}

// ---------------------------------------------------------------------------
extern "C" void kernel_launch(void* const* d_in, const int* in_sizes, int n_in,
                              void* d_out, int out_size, void* d_ws, size_t ws_size,
                              hipStream_t stream)
{
    const float* query  = (const float*)d_in[0];
    const float* f0     = (const float*)d_in[1];
    const float* f1     = (const float*)d_in[2];
    const float* f2     = (const float*)d_in[3];
    const float* f3     = (const float*)d_in[4];
    const float* refp   = (const float*)d_in[5];
    const float* W_off  = (const float*)d_in[6];
    const float* b_off  = (const float*)d_in[7];
    const float* W_attn = (const float*)d_in[8];
    const float* b_attn = (const float*)d_in[9];
    const float* W_out  = (const float*)d_in[10];
    const float* b_out  = (const float*)d_in[11];

    float* out      = (float*)d_out;                       // (B,Q,256)
    float* attn_out = out + (size_t)BQ * 256;              // (B,Q,8,4,4)

    // Workspace layout (bytes):
    char* w = (char*)d_ws;
    float* offs          = (float*)(w + 0);                 // 44,564,480
    unsigned short* ft   = (unsigned short*)(w + 44564480); // 22,282,240
    unsigned short* aggb = (unsigned short*)(w + 66846720); // 22,282,240
    unsigned short* Wcat = (unsigned short*)(w + 89128960); // 196,608 [384][256] hi
    unsigned short* Wlo  = (unsigned short*)(w + 89325568); // 131,072 [256][256] lo
    unsigned short* wout = (unsigned short*)(w + 89456640); // 131,072
    int* hist            = (int*)(w + 89587712);            //   2,048
    int* cursor          = (int*)(w + 89589760);            //   2,048
    int* order           = (int*)(w + 89591808);            // 174,080

    // query bucketing (independent chain)
    zero_hist_kernel<<<1, 512, 0, stream>>>(hist);
    hist_kernel<<<170, 256, 0, stream>>>(refp, hist);
    scan_kernel<<<1, 512, 0, stream>>>(hist, cursor);
    scatter_kernel<<<170, 256, 0, stream>>>(refp, cursor, order);

    feat_transpose_kernel<<<dim3(1360, 8), 256, 0, stream>>>(f0, f1, f2, f3, ft);
    wsplit_kernel<<<dim3(8, 8), 256, 0, stream>>>(W_off, Wcat, Wlo, 256, 1);
    wsplit_kernel<<<dim3(4, 8), 256, 0, stream>>>(W_attn, Wcat + 256 * 256, Wlo, 128, 0);
    wsplit_kernel<<<dim3(8, 8), 256, 0, stream>>>(W_out, wout, wout, 256, 0);

    // fused: offsets (split-precision + tanh) + attn scores + softmax
    qproj_kernel<<<dim3(680), 256, 0, stream>>>(
        query, Wcat, Wlo, b_off, b_attn, offs, attn_out);

    // sampling + aggregation -> agg bf16
    sample_kernel<<<dim3(10880), 256, 0, stream>>>(
        offs, attn_out, refp, ft, order, aggb);

    // out = agg @ W_out + b_out
    mfma_gemm<<<dim3(340, 2), 256, 0, stream>>>(aggb, wout, b_out, out, 256);
}